// Round 12
// baseline (279.104 us; speedup 1.0000x reference)
//
#include <hip/hip_runtime.h>
#include <hip/hip_bf16.h>

// TemporalEncoderLayer: LN1 -> QKV -> windowed+global attention -> Wo+res -> LN2 -> GELU MLP + res
// B=2 S=2048 D=1024 H=16 DH=64 HALF_WIN=256. fp32 I/O, bf16 MFMA compute.

typedef __bf16 bf16x8 __attribute__((ext_vector_type(8)));
typedef float f32x4 __attribute__((ext_vector_type(4)));
typedef unsigned short u16;
typedef u16 u16x8 __attribute__((ext_vector_type(8)));
typedef u16 u16x4 __attribute__((ext_vector_type(4)));
typedef unsigned long long u64;

#define MBYTE (1ull << 20)

static __device__ __forceinline__ u16 f2bf(float f) {
  union { __hip_bfloat16 h; u16 u; } cv;
  cv.h = __float2bfloat16(f);
  return cv.u;
}

static __device__ __forceinline__ float fexp2(float x) {
#if __has_builtin(__builtin_amdgcn_exp2f)
  return __builtin_amdgcn_exp2f(x);
#else
  return __expf(x * 0.6931471805599453f);
#endif
}

// tanh-form GELU via exp2 (~11 VALU ops vs ~25-30 for erff; max abs err ~1.5e-3)
static __device__ __forceinline__ float fast_gelu(float v) {
  float u = v * (0.7978845608028654f + 0.035677408136300125f * v * v);
  float e = fexp2(u * 2.885390081777927f);  // exp(2u)
  float th = 1.0f - 2.0f / (e + 1.0f);      // tanh(u)
  return 0.5f * v * (1.0f + th);
}

static __device__ __forceinline__ void gl_lds16(const void* g, void* l) {
  __builtin_amdgcn_global_load_lds((const __attribute__((address_space(1))) unsigned int*)g,
                                   (__attribute__((address_space(3))) unsigned int*)l, 16, 0, 0);
}

// XCD-aware block swizzle (grid % 8 == 0): contiguous tile chunk per XCD L2.
static __device__ __forceinline__ int xcd_swz(int bid, int nwg) {
  return (bid & 7) * (nwg >> 3) + (bid >> 3);
}

// ---------------- small utility kernels ----------------

// blocks 0..11: concat bias (3072 elems). block 12: detect is_global layout + pack bitmask.
__global__ void prep_small(const unsigned char* __restrict__ g, u64* __restrict__ isgq,
                           const float* __restrict__ bq, const float* __restrict__ bk,
                           const float* __restrict__ bv, float* __restrict__ bias) {
  int t = threadIdx.x;
  if (blockIdx.x < 12) {
    int i = blockIdx.x * 256 + t;
    float v = (i < 1024) ? bq[i] : (i < 2048) ? bk[i - 1024] : bv[i - 2048];
    bias[i] = v;
    return;
  }
  unsigned int acc = 0;
  for (int i = t; i < 4096; i += 256)
    if (i & 3) acc |= g[i];
  unsigned long long any = __ballot(acc != 0);
  __shared__ unsigned int r4[4];
  if ((t & 63) == 0) r4[t >> 6] = (any != 0) ? 1u : 0u;
  __syncthreads();
  int isInt = (r4[0] | r4[1] | r4[2] | r4[3]) ? 0 : 1;
  if (t < 64) {
    const int* g32 = (const int*)g;
    u64 w = 0;
    for (int j = 0; j < 64; ++j) {
      int idx = t * 64 + j;
      int v = isInt ? g32[idx] : (int)g[idx];
      w |= (u64)(v != 0 ? 1u : 0u) << j;
    }
    isgq[t] = w;
  }
}

// All 6 weight transposes in one kernel (fp32 [R][C] -> bf16 [C][R]):
// blocks [0,4096): Wq/Wk/Wv/Wo (1024x1024 each) -> wqkvo stacked
// blocks [4096,8192): W1 (1024x4096) -> w1t ; [8192,12288): W2 (4096x1024) -> w2t
__global__ __launch_bounds__(256, 4) void transpose_all(
    const float* __restrict__ s0, const float* __restrict__ s1, const float* __restrict__ s2,
    const float* __restrict__ s3, const float* __restrict__ w1, const float* __restrict__ w2,
    u16* __restrict__ dqkvo, u16* __restrict__ d1, u16* __restrict__ d2) {
  __shared__ float tile[32][33];
  int bid = blockIdx.x;
  const float* src;
  u16* dst;
  int R, C, local;
  if (bid < 4096) {
    int sel = bid >> 10;
    src = (sel == 0) ? s0 : (sel == 1) ? s1 : (sel == 2) ? s2 : s3;
    dst = dqkvo + (size_t)sel * 1024 * 1024;
    R = 1024; C = 1024; local = bid & 1023;
  } else if (bid < 8192) {
    src = w1; dst = d1; R = 1024; C = 4096; local = bid - 4096;
  } else {
    src = w2; dst = d2; R = 4096; C = 1024; local = bid - 8192;
  }
  int nCx = C >> 5;
  int bx = local % nCx, by = local / nCx;
  int tx = threadIdx.x & 31, ty = threadIdx.x >> 5;
#pragma unroll
  for (int i = 0; i < 32; i += 8)
    tile[ty + i][tx] = src[(size_t)(by * 32 + ty + i) * C + bx * 32 + tx];
  __syncthreads();
#pragma unroll
  for (int i = 0; i < 32; i += 8)
    dst[(size_t)(bx * 32 + ty + i) * R + by * 32 + tx] = f2bf(tile[tx][ty + i]);
}

// LayerNorm fp32 [4096][1024] -> bf16 [4096][1024]
__global__ __launch_bounds__(256, 4) void layernorm_k(const float* __restrict__ x,
                                                      const float* __restrict__ gam,
                                                      const float* __restrict__ bet,
                                                      u16* __restrict__ out) {
  int row = blockIdx.x, t = threadIdx.x;
  const float4* xr = (const float4*)(x + (size_t)row * 1024);
  float4 v = xr[t];
  float s = v.x + v.y + v.z + v.w;
  float ss = v.x * v.x + v.y * v.y + v.z * v.z + v.w * v.w;
#pragma unroll
  for (int d = 1; d < 64; d <<= 1) {
    s += __shfl_xor(s, d);
    ss += __shfl_xor(ss, d);
  }
  __shared__ float ps[8];
  int w = t >> 6, l = t & 63;
  if (l == 0) { ps[w] = s; ps[4 + w] = ss; }
  __syncthreads();
  s = ps[0] + ps[1] + ps[2] + ps[3];
  ss = ps[4] + ps[5] + ps[6] + ps[7];
  float mean = s * (1.0f / 1024.0f);
  float var = ss * (1.0f / 1024.0f) - mean * mean;
  float rstd = rsqrtf(var + 1e-5f);
  float4 gv = ((const float4*)gam)[t];
  float4 bv = ((const float4*)bet)[t];
  u16x4 o;
  o[0] = f2bf((v.x - mean) * rstd * gv.x + bv.x);
  o[1] = f2bf((v.y - mean) * rstd * gv.y + bv.y);
  o[2] = f2bf((v.z - mean) * rstd * gv.z + bv.z);
  o[3] = f2bf((v.w - mean) * rstd * gv.w + bv.w);
  *(u16x4*)(out + (size_t)row * 1024 + t * 4) = o;
}

// V slice of qkv [4096][3072] (cols 2048..3071) -> vt [B*H*64][2048]
__global__ __launch_bounds__(256, 4) void transpose_v(const u16* __restrict__ qkv,
                                                      u16* __restrict__ vt) {
  __shared__ u16 tile[64][64];
  int blk = blockIdx.x;
  int st = blk & 31, hh = (blk >> 5) & 15, b = blk >> 9;
  int t = threadIdx.x;
  int r = t >> 2, cc = (t & 3) * 16;
  const u16* src = qkv + (size_t)(b * 2048 + st * 64 + r) * 3072 + 2048 + hh * 64 + cc;
  u16x8 v0 = *(const u16x8*)src;
  u16x8 v1 = *(const u16x8*)(src + 8);
  *(u16x8*)&tile[r][cc] = v0;
  *(u16x8*)&tile[r][cc + 8] = v1;
  __syncthreads();
  int dh = t >> 2, sc = (t & 3) * 16;
  u16x8 o0, o1;
#pragma unroll
  for (int j = 0; j < 8; ++j) o0[j] = tile[sc + j][dh];
#pragma unroll
  for (int j = 0; j < 8; ++j) o1[j] = tile[sc + 8 + j][dh];
  u16* dst = vt + (size_t)((b * 16 + hh) * 64 + dh) * 2048 + st * 64 + sc;
  *(u16x8*)dst = o0;
  *(u16x8*)(dst + 8) = o1;
}

// ---------------- GEMM: C[M][N] = A[M][K](bf16) * Bt[N][K]^T + bias (+gelu) (+res) ----------------
// R8/R10 configuration verbatim (proven best): MT*32 x 128 tile, BK=32, 4 waves 2x2,
// 2-phase dbuf, one __syncthreads per iter; LDS chunk swizzle phys = logical ^ ((row>>1)&3)
// via pre-swizzled global source + linear LDS dest (conflict-free, measured 0).
// R9 lesson: min-waves 5/6 -> VGPR cap ~48 < acc(64) -> scratch spill. Keep (3,4).
// R11 lesson: 256-tile fine-phase (10 barriers/K-tile, 1 blk/CU) loses to this simple form.
template <int MT, int OUTMODE, bool DOGELU, bool DORES>
__global__ __launch_bounds__(256, (MT == 4) ? 3 : 4) void gemm_bt(
    const u16* __restrict__ A, const u16* __restrict__ Bt, const float* __restrict__ bias,
    const float* __restrict__ res, void* __restrict__ Cout, int M, int N, int K) {
  constexpr int BM = MT * 32;
  constexpr int MR = MT;
  constexpr int SI = MT / 2;
  __shared__ u16 As[2][BM * 32];
  __shared__ u16 Bs[2][128 * 32];
  const int t = threadIdx.x;
  const int w = t >> 6, l = t & 63, g = l >> 4, c = l & 15;
  const int wr = w >> 1, wc = w & 1;
  const int nTn = N >> 7;
  const int bid = xcd_swz(blockIdx.x, gridDim.x);
  const int tm = bid / nTn, tn = bid % nTn;

  f32x4 acc[MR][4];
#pragma unroll
  for (int m = 0; m < MR; ++m)
#pragma unroll
    for (int n = 0; n < 4; ++n) acc[m][n] = (f32x4){0.f, 0.f, 0.f, 0.f};

  const int srow = t >> 2, schunk = t & 3;

#define GSTAGE(buf, k0)                                                                   \
  {                                                                                       \
    _Pragma("unroll") for (int i = 0; i < SI; ++i) {                                      \
      int r_ = srow + i * 64;                                                             \
      int ch_ = schunk ^ ((r_ >> 1) & 3);                                                 \
      gl_lds16(A + (size_t)(tm * BM + r_) * K + (k0) + ch_ * 8,                           \
               (u16*)As[buf] + r_ * 32 + schunk * 8);                                     \
    }                                                                                     \
    _Pragma("unroll") for (int i = 0; i < 2; ++i) {                                       \
      int r_ = srow + i * 64;                                                             \
      int ch_ = schunk ^ ((r_ >> 1) & 3);                                                 \
      gl_lds16(Bt + (size_t)(tn * 128 + r_) * K + (k0) + ch_ * 8,                         \
               (u16*)Bs[buf] + r_ * 32 + schunk * 8);                                     \
    }                                                                                     \
  }

  const int nt = K >> 5;
  GSTAGE(0, 0);
  __syncthreads();
  int cur = 0;

  for (int it = 0; it < nt; ++it) {
    if (it + 1 < nt) GSTAGE(cur ^ 1, (it + 1) * 32);
    bf16x8 af[MR], bfr[4];
#pragma unroll
    for (int m = 0; m < MR; ++m) {
      int ar = wr * (MT * 16) + m * 16 + c;
      af[m] = *(const bf16x8*)(As[cur] + ar * 32 + (g ^ ((ar >> 1) & 3)) * 8);
    }
#pragma unroll
    for (int n = 0; n < 4; ++n) {
      int br = wc * 64 + n * 16 + c;
      bfr[n] = *(const bf16x8*)(Bs[cur] + br * 32 + (g ^ ((br >> 1) & 3)) * 8);
    }
#pragma unroll
    for (int m = 0; m < MR; ++m)
#pragma unroll
      for (int n = 0; n < 4; ++n)
        acc[m][n] = __builtin_amdgcn_mfma_f32_16x16x32_bf16(af[m], bfr[n], acc[m][n], 0, 0, 0);
    __syncthreads();
    cur ^= 1;
  }
#undef GSTAGE

#pragma unroll
  for (int m = 0; m < MR; ++m) {
    int grow0 = tm * BM + wr * (MT * 16) + m * 16 + g * 4;
#pragma unroll
    for (int n = 0; n < 4; ++n) {
      int gcol = tn * 128 + wc * 64 + n * 16 + c;
      float bv = bias[gcol];
#pragma unroll
      for (int r = 0; r < 4; ++r) {
        int grow = grow0 + r;
        float v = acc[m][n][r] + bv;
        if (DOGELU) v = fast_gelu(v);
        if (DORES) v += res[(size_t)grow * N + gcol];
        if (OUTMODE == 1)
          ((u16*)Cout)[(size_t)grow * N + gcol] = f2bf(v);
        else
          ((float*)Cout)[(size_t)grow * N + gcol] = v;
      }
    }
  }
}

// ---------------- fused windowed+global attention ----------------
// R10 structure (8-wave, QBLK=128, dbuf K/V, no-max exp2 softmax, row-sum via ones-MFMA).
// R12: per-(kt,r) allowed-mask bit-words (window-range | k-global | q-global), pre-shifted
// by lane's c. Per-element mask test = constant shift+and+select (~1-2 VALU) instead of
// ~6 (d add, range add/cmp, 64-bit kw shift, or, select). exp2 computed unconditionally
// (scores bounded |sf|<~10), zero-selected after.
__global__ __launch_bounds__(512, 4) void attn_fwd(const u16* __restrict__ qkv,
                                                   const u16* __restrict__ vt,
                                                   const u64* __restrict__ isgq,
                                                   u16* __restrict__ ctx) {
  __shared__ u16 Ks[2][64 * 64];   // [s][dh], chunk-XOR swizzled by (s&7)
  __shared__ u16 Vs[2][64 * 64];   // [dh][s], chunk-XOR swizzled by (dh&7)
  __shared__ u16 Ps[8][16 * 64];   // per-wave P, [q][s], swizzled by (q&7)
  const int t = threadIdx.x, w = t >> 6, l = t & 63, g = l >> 4, c = l & 15;
  const int bid = xcd_swz(blockIdx.x, 512);
  const int qb = bid & 15, h = (bid >> 4) & 15, b = bid >> 8;
  const int q0 = qb * 128 + w * 16;
  const float C2 = 0.18033688011112042f;  // 0.125 * log2(e)

  bf16x8 aq[2];
#pragma unroll
  for (int kf = 0; kf < 2; ++kf) {
    bf16x8 raw = *(const bf16x8*)(qkv + (size_t)(b * 2048 + q0 + c) * 3072 +
                                  h * 64 + kf * 32 + g * 8);
#pragma unroll
    for (int j = 0; j < 8; ++j) aq[kf][j] = (__bf16)((float)raw[j] * C2);
  }

  const u64 qw = isgq[b * 32 + (q0 >> 6)];
  bool qflag[4];
#pragma unroll
  for (int r = 0; r < 4; ++r) qflag[r] = (qw >> ((q0 & 63) + g * 4 + r)) & 1;

  bf16x8 vone;
#pragma unroll
  for (int j = 0; j < 8; ++j) vone[j] = (__bf16)1.0f;

  int poff[4][4];
#pragma unroll
  for (int n = 0; n < 4; ++n)
#pragma unroll
    for (int r = 0; r < 4; ++r) {
      int qr = g * 4 + r, scol = n * 16 + c;
      poff[n][r] = qr * 128 + ((scol * 2) ^ ((qr & 7) << 4));
    }

  f32x4 o[4], ol;
#pragma unroll
  for (int n = 0; n < 4; ++n) o[n] = (f32x4){0.f, 0.f, 0.f, 0.f};
  ol = (f32x4){0.f, 0.f, 0.f, 0.f};

  const int stR = t >> 3, stC = t & 7;
  const int qa0 = q0 + g * 4;

#define STAGE(buf, kt)                                                                       \
  {                                                                                          \
    int ch_ = stC ^ (stR & 7);                                                               \
    gl_lds16(qkv + (size_t)(b * 2048 + (kt)*64 + stR) * 3072 + 1024 + h * 64 + ch_ * 8,      \
             (u16*)Ks[buf] + stR * 64 + stC * 8);                                            \
    gl_lds16(vt + (size_t)((b * 16 + h) * 64 + stR) * 2048 + (kt)*64 + ch_ * 8,              \
             (u16*)Vs[buf] + stR * 64 + stC * 8);                                            \
  }

  STAGE(0, 0);
  __syncthreads();
  int cur = 0;

  for (int kt = 0; kt < 32; ++kt) {
    if (kt + 1 < 32) STAGE(cur ^ 1, kt + 1);
    const u64 kw = isgq[b * 32 + kt];

    // QK^T: S[16 q][64 k] (already x 0.125*log2e via prescaled Q)
    f32x4 sf[4];
#pragma unroll
    for (int n = 0; n < 4; ++n) sf[n] = (f32x4){0.f, 0.f, 0.f, 0.f};
#pragma unroll
    for (int n = 0; n < 4; ++n) {
      int srw = n * 16 + c;
#pragma unroll
      for (int kf = 0; kf < 2; ++kf) {
        bf16x8 kb = *(const bf16x8*)((const char*)Ks[cur] + srw * 128 +
                                     ((kf * 64 + g * 16) ^ ((srw & 7) << 4)));
        sf[n] = __builtin_amdgcn_mfma_f32_16x16x32_bf16(aq[kf], kb, sf[n], 0, 0, 0);
      }
    }

    // allowed-mask words: bit j of am[r] = allowed(q=qa0+r, k=kt*64+j); pre-shift by c.
    u64 sm[4];
#pragma unroll
    for (int r = 0; r < 4; ++r) {
      int qa = qa0 + r;
      int lo = qa - 256 - kt * 64;   // window low bit (inclusive)
      int hi = qa + 256 - kt * 64;   // window high bit (inclusive)
      u64 wlow = (lo <= 0) ? ~0ull : ((lo >= 64) ? 0ull : (~0ull << lo));
      u64 whigh = (hi >= 63) ? ~0ull : ((hi < 0) ? 0ull : (~0ull >> (63 - hi)));
      u64 am = qflag[r] ? ~0ull : ((wlow & whigh) | kw);
      sm[r] = am >> c;
    }

    // exp2 + mask-select + store P (bf16)
#pragma unroll
    for (int n = 0; n < 4; ++n) {
#pragma unroll
      for (int r = 0; r < 4; ++r) {
        float e = fexp2(sf[n][r]);
        float p = ((sm[r] >> (n * 16)) & 1) ? e : 0.0f;
        *(u16*)((char*)Ps[w] + poff[n][r]) = f2bf(p);
      }
    }

    // PV: O += P[16][64] * V[64][64]^T; l += P * ones (same pa fragment)
#pragma unroll
    for (int kf = 0; kf < 2; ++kf) {
      bf16x8 pa = *(const bf16x8*)((const char*)Ps[w] + c * 128 +
                                   ((kf * 64 + g * 16) ^ ((c & 7) << 4)));
#pragma unroll
      for (int n = 0; n < 4; ++n) {
        int dh = n * 16 + c;
        bf16x8 vb = *(const bf16x8*)((const char*)Vs[cur] + dh * 128 +
                                     ((kf * 64 + g * 16) ^ ((dh & 7) << 4)));
        o[n] = __builtin_amdgcn_mfma_f32_16x16x32_bf16(pa, vb, o[n], 0, 0, 0);
      }
      ol = __builtin_amdgcn_mfma_f32_16x16x32_bf16(pa, vone, ol, 0, 0, 0);
    }
    __syncthreads();
    cur ^= 1;
  }
#undef STAGE

#pragma unroll
  for (int r = 0; r < 4; ++r) {
    float inv = 1.0f / ol[r];
    int qg = q0 + g * 4 + r;
#pragma unroll
    for (int n = 0; n < 4; ++n)
      ctx[(size_t)(b * 2048 + qg) * 1024 + h * 64 + n * 16 + c] = f2bf(o[n][r] * inv);
  }
}

// ---------------- launcher ----------------

extern "C" void kernel_launch(void* const* d_in, const int* in_sizes, int n_in,
                              void* d_out, int out_size, void* d_ws, size_t ws_size,
                              hipStream_t stream) {
  (void)in_sizes; (void)n_in; (void)out_size; (void)ws_size;
  const float* x = (const float*)d_in[0];
  const unsigned char* isg = (const unsigned char*)d_in[1];
  const float* Wq = (const float*)d_in[2];
  const float* bq = (const float*)d_in[3];
  const float* Wk = (const float*)d_in[4];
  const float* bk = (const float*)d_in[5];
  const float* Wv = (const float*)d_in[6];
  const float* bv = (const float*)d_in[7];
  const float* Wo = (const float*)d_in[8];
  const float* bo = (const float*)d_in[9];
  const float* ln1g = (const float*)d_in[10];
  const float* ln1b = (const float*)d_in[11];
  const float* ln2g = (const float*)d_in[12];
  const float* ln2b = (const float*)d_in[13];
  const float* W1 = (const float*)d_in[14];
  const float* b1 = (const float*)d_in[15];
  const float* W2 = (const float*)d_in[16];
  const float* b2 = (const float*)d_in[17];

  char* ws = (char*)d_ws;
  u16* wqkvt = (u16*)(ws);                    // [3072][1024] bf16, 6MB (wot follows contiguously)
  u16* wot   = (u16*)(ws + 6 * MBYTE);        // [1024][1024], 2MB
  u16* w1t   = (u16*)(ws + 8 * MBYTE);        // [4096][1024], 8MB
  u16* w2t   = (u16*)(ws + 16 * MBYTE);       // [1024][4096], 8MB
  float* bqkv = (float*)(ws + 24 * MBYTE);    // [3072]
  u64* isgq  = (u64*)(ws + 24 * MBYTE + 65536);  // 64 qwords
  u16* hbuf  = (u16*)(ws + 25 * MBYTE);       // [4096][1024] bf16 (h, then h2)
  u16* qkvb  = (u16*)(ws + 33 * MBYTE);       // [4096][3072] bf16, 24MB
  u16* vtb   = (u16*)(ws + 57 * MBYTE);       // [B*H*64][2048] bf16, 8MB
  u16* ctx   = (u16*)(ws + 65 * MBYTE);       // [4096][1024] bf16, 8MB
  float* x1  = (float*)(ws + 73 * MBYTE);     // [4096][1024] f32, 16MB
  u16* ff1   = (u16*)(ws + 33 * MBYTE);       // [4096][4096] bf16, 32MB (aliases qkv+vt, dead by then)

  prep_small<<<13, 256, 0, stream>>>(isg, isgq, bq, bk, bv, bqkv);
  transpose_all<<<12288, 256, 0, stream>>>(Wq, Wk, Wv, Wo, W1, W2, wqkvt, w1t, w2t);

  layernorm_k<<<4096, 256, 0, stream>>>(x, ln1g, ln1b, hbuf);
  gemm_bt<4, 1, false, false><<<768, 256, 0, stream>>>(hbuf, wqkvt, bqkv, nullptr, qkvb,
                                                       4096, 3072, 1024);
  transpose_v<<<1024, 256, 0, stream>>>(qkvb, vtb);
  attn_fwd<<<512, 512, 0, stream>>>(qkvb, vtb, isgq, ctx);
  gemm_bt<2, 0, false, true><<<512, 256, 0, stream>>>(ctx, wot, bo, x, x1, 4096, 1024, 1024);
  layernorm_k<<<4096, 256, 0, stream>>>(x1, ln2g, ln2b, hbuf);
  gemm_bt<4, 1, true, false><<<1024, 256, 0, stream>>>(hbuf, w1t, b1, nullptr, ff1,
                                                       4096, 4096, 1024);
  gemm_bt<2, 0, false, true><<<512, 256, 0, stream>>>(ff1, w2t, b2, x1, (float*)d_out,
                                                      4096, 1024, 4096);
}

// Round 13
// 266.850 us; speedup vs baseline: 1.0459x; 1.0459x over previous
//
#include <hip/hip_runtime.h>
#include <hip/hip_bf16.h>

// TemporalEncoderLayer: LN1 -> QKV -> windowed+global attention -> Wo+res -> LN2 -> GELU MLP + res
// B=2 S=2048 D=1024 H=16 DH=64 HALF_WIN=256. fp32 I/O, bf16 MFMA compute.
// R13 = consolidated best: R10 attn body + R10 gemm config + R12 launch merges.

typedef __bf16 bf16x8 __attribute__((ext_vector_type(8)));
typedef float f32x4 __attribute__((ext_vector_type(4)));
typedef unsigned short u16;
typedef u16 u16x8 __attribute__((ext_vector_type(8)));
typedef u16 u16x4 __attribute__((ext_vector_type(4)));
typedef unsigned long long u64;

#define MBYTE (1ull << 20)

static __device__ __forceinline__ u16 f2bf(float f) {
  union { __hip_bfloat16 h; u16 u; } cv;
  cv.h = __float2bfloat16(f);
  return cv.u;
}

static __device__ __forceinline__ float fexp2(float x) {
#if __has_builtin(__builtin_amdgcn_exp2f)
  return __builtin_amdgcn_exp2f(x);
#else
  return __expf(x * 0.6931471805599453f);
#endif
}

// tanh-form GELU via exp2 (~11 VALU ops vs ~25-30 for erff; max abs err ~1.5e-3)
static __device__ __forceinline__ float fast_gelu(float v) {
  float u = v * (0.7978845608028654f + 0.035677408136300125f * v * v);
  float e = fexp2(u * 2.885390081777927f);  // exp(2u)
  float th = 1.0f - 2.0f / (e + 1.0f);      // tanh(u)
  return 0.5f * v * (1.0f + th);
}

static __device__ __forceinline__ void gl_lds16(const void* g, void* l) {
  __builtin_amdgcn_global_load_lds((const __attribute__((address_space(1))) unsigned int*)g,
                                   (__attribute__((address_space(3))) unsigned int*)l, 16, 0, 0);
}

// XCD-aware block swizzle (grid % 8 == 0): contiguous tile chunk per XCD L2.
static __device__ __forceinline__ int xcd_swz(int bid, int nwg) {
  return (bid & 7) * (nwg >> 3) + (bid >> 3);
}

// ---------------- small utility kernels ----------------

// blocks 0..11: concat bias (3072 elems). block 12: detect is_global layout + pack bitmask.
__global__ void prep_small(const unsigned char* __restrict__ g, u64* __restrict__ isgq,
                           const float* __restrict__ bq, const float* __restrict__ bk,
                           const float* __restrict__ bv, float* __restrict__ bias) {
  int t = threadIdx.x;
  if (blockIdx.x < 12) {
    int i = blockIdx.x * 256 + t;
    float v = (i < 1024) ? bq[i] : (i < 2048) ? bk[i - 1024] : bv[i - 2048];
    bias[i] = v;
    return;
  }
  unsigned int acc = 0;
  for (int i = t; i < 4096; i += 256)
    if (i & 3) acc |= g[i];
  unsigned long long any = __ballot(acc != 0);
  __shared__ unsigned int r4[4];
  if ((t & 63) == 0) r4[t >> 6] = (any != 0) ? 1u : 0u;
  __syncthreads();
  int isInt = (r4[0] | r4[1] | r4[2] | r4[3]) ? 0 : 1;
  if (t < 64) {
    const int* g32 = (const int*)g;
    u64 w = 0;
    for (int j = 0; j < 64; ++j) {
      int idx = t * 64 + j;
      int v = isInt ? g32[idx] : (int)g[idx];
      w |= (u64)(v != 0 ? 1u : 0u) << j;
    }
    isgq[t] = w;
  }
}

// All 6 weight transposes in one kernel (fp32 [R][C] -> bf16 [C][R]):
// blocks [0,4096): Wq/Wk/Wv/Wo (1024x1024 each) -> wqkvo stacked
// blocks [4096,8192): W1 (1024x4096) -> w1t ; [8192,12288): W2 (4096x1024) -> w2t
__global__ __launch_bounds__(256, 4) void transpose_all(
    const float* __restrict__ s0, const float* __restrict__ s1, const float* __restrict__ s2,
    const float* __restrict__ s3, const float* __restrict__ w1, const float* __restrict__ w2,
    u16* __restrict__ dqkvo, u16* __restrict__ d1, u16* __restrict__ d2) {
  __shared__ float tile[32][33];
  int bid = blockIdx.x;
  const float* src;
  u16* dst;
  int R, C, local;
  if (bid < 4096) {
    int sel = bid >> 10;
    src = (sel == 0) ? s0 : (sel == 1) ? s1 : (sel == 2) ? s2 : s3;
    dst = dqkvo + (size_t)sel * 1024 * 1024;
    R = 1024; C = 1024; local = bid & 1023;
  } else if (bid < 8192) {
    src = w1; dst = d1; R = 1024; C = 4096; local = bid - 4096;
  } else {
    src = w2; dst = d2; R = 4096; C = 1024; local = bid - 8192;
  }
  int nCx = C >> 5;
  int bx = local % nCx, by = local / nCx;
  int tx = threadIdx.x & 31, ty = threadIdx.x >> 5;
#pragma unroll
  for (int i = 0; i < 32; i += 8)
    tile[ty + i][tx] = src[(size_t)(by * 32 + ty + i) * C + bx * 32 + tx];
  __syncthreads();
#pragma unroll
  for (int i = 0; i < 32; i += 8)
    dst[(size_t)(bx * 32 + ty + i) * R + by * 32 + tx] = f2bf(tile[tx][ty + i]);
}

// LayerNorm fp32 [4096][1024] -> bf16 [4096][1024]
__global__ __launch_bounds__(256, 4) void layernorm_k(const float* __restrict__ x,
                                                      const float* __restrict__ gam,
                                                      const float* __restrict__ bet,
                                                      u16* __restrict__ out) {
  int row = blockIdx.x, t = threadIdx.x;
  const float4* xr = (const float4*)(x + (size_t)row * 1024);
  float4 v = xr[t];
  float s = v.x + v.y + v.z + v.w;
  float ss = v.x * v.x + v.y * v.y + v.z * v.z + v.w * v.w;
#pragma unroll
  for (int d = 1; d < 64; d <<= 1) {
    s += __shfl_xor(s, d);
    ss += __shfl_xor(ss, d);
  }
  __shared__ float ps[8];
  int w = t >> 6, l = t & 63;
  if (l == 0) { ps[w] = s; ps[4 + w] = ss; }
  __syncthreads();
  s = ps[0] + ps[1] + ps[2] + ps[3];
  ss = ps[4] + ps[5] + ps[6] + ps[7];
  float mean = s * (1.0f / 1024.0f);
  float var = ss * (1.0f / 1024.0f) - mean * mean;
  float rstd = rsqrtf(var + 1e-5f);
  float4 gv = ((const float4*)gam)[t];
  float4 bv = ((const float4*)bet)[t];
  u16x4 o;
  o[0] = f2bf((v.x - mean) * rstd * gv.x + bv.x);
  o[1] = f2bf((v.y - mean) * rstd * gv.y + bv.y);
  o[2] = f2bf((v.z - mean) * rstd * gv.z + bv.z);
  o[3] = f2bf((v.w - mean) * rstd * gv.w + bv.w);
  *(u16x4*)(out + (size_t)row * 1024 + t * 4) = o;
}

// V slice of qkv [4096][3072] (cols 2048..3071) -> vt [B*H*64][2048]
__global__ __launch_bounds__(256, 4) void transpose_v(const u16* __restrict__ qkv,
                                                      u16* __restrict__ vt) {
  __shared__ u16 tile[64][64];
  int blk = blockIdx.x;
  int st = blk & 31, hh = (blk >> 5) & 15, b = blk >> 9;
  int t = threadIdx.x;
  int r = t >> 2, cc = (t & 3) * 16;
  const u16* src = qkv + (size_t)(b * 2048 + st * 64 + r) * 3072 + 2048 + hh * 64 + cc;
  u16x8 v0 = *(const u16x8*)src;
  u16x8 v1 = *(const u16x8*)(src + 8);
  *(u16x8*)&tile[r][cc] = v0;
  *(u16x8*)&tile[r][cc + 8] = v1;
  __syncthreads();
  int dh = t >> 2, sc = (t & 3) * 16;
  u16x8 o0, o1;
#pragma unroll
  for (int j = 0; j < 8; ++j) o0[j] = tile[sc + j][dh];
#pragma unroll
  for (int j = 0; j < 8; ++j) o1[j] = tile[sc + 8 + j][dh];
  u16* dst = vt + (size_t)((b * 16 + hh) * 64 + dh) * 2048 + st * 64 + sc;
  *(u16x8*)dst = o0;
  *(u16x8*)(dst + 8) = o1;
}

// ---------------- GEMM: C[M][N] = A[M][K](bf16) * Bt[N][K]^T + bias (+gelu) (+res) ----------------
// R8/R10 configuration verbatim (proven best): MT*32 x 128 tile, BK=32, 4 waves 2x2,
// 2-phase dbuf, one __syncthreads per iter; LDS chunk swizzle phys = logical ^ ((row>>1)&3)
// via pre-swizzled global source + linear LDS dest (conflict-free, measured 0).
// R9 lesson: min-waves 5/6 -> VGPR cap ~48 < acc(64) -> scratch spill. Keep (3,4).
// R11 lesson: 256-tile fine-phase (10 barriers/K-tile, 1 blk/CU) loses to this simple form.
template <int MT, int OUTMODE, bool DOGELU, bool DORES>
__global__ __launch_bounds__(256, (MT == 4) ? 3 : 4) void gemm_bt(
    const u16* __restrict__ A, const u16* __restrict__ Bt, const float* __restrict__ bias,
    const float* __restrict__ res, void* __restrict__ Cout, int M, int N, int K) {
  constexpr int BM = MT * 32;
  constexpr int MR = MT;
  constexpr int SI = MT / 2;
  __shared__ u16 As[2][BM * 32];
  __shared__ u16 Bs[2][128 * 32];
  const int t = threadIdx.x;
  const int w = t >> 6, l = t & 63, g = l >> 4, c = l & 15;
  const int wr = w >> 1, wc = w & 1;
  const int nTn = N >> 7;
  const int bid = xcd_swz(blockIdx.x, gridDim.x);
  const int tm = bid / nTn, tn = bid % nTn;

  f32x4 acc[MR][4];
#pragma unroll
  for (int m = 0; m < MR; ++m)
#pragma unroll
    for (int n = 0; n < 4; ++n) acc[m][n] = (f32x4){0.f, 0.f, 0.f, 0.f};

  const int srow = t >> 2, schunk = t & 3;

#define GSTAGE(buf, k0)                                                                   \
  {                                                                                       \
    _Pragma("unroll") for (int i = 0; i < SI; ++i) {                                      \
      int r_ = srow + i * 64;                                                             \
      int ch_ = schunk ^ ((r_ >> 1) & 3);                                                 \
      gl_lds16(A + (size_t)(tm * BM + r_) * K + (k0) + ch_ * 8,                           \
               (u16*)As[buf] + r_ * 32 + schunk * 8);                                     \
    }                                                                                     \
    _Pragma("unroll") for (int i = 0; i < 2; ++i) {                                       \
      int r_ = srow + i * 64;                                                             \
      int ch_ = schunk ^ ((r_ >> 1) & 3);                                                 \
      gl_lds16(Bt + (size_t)(tn * 128 + r_) * K + (k0) + ch_ * 8,                         \
               (u16*)Bs[buf] + r_ * 32 + schunk * 8);                                     \
    }                                                                                     \
  }

  const int nt = K >> 5;
  GSTAGE(0, 0);
  __syncthreads();
  int cur = 0;

  for (int it = 0; it < nt; ++it) {
    if (it + 1 < nt) GSTAGE(cur ^ 1, (it + 1) * 32);
    bf16x8 af[MR], bfr[4];
#pragma unroll
    for (int m = 0; m < MR; ++m) {
      int ar = wr * (MT * 16) + m * 16 + c;
      af[m] = *(const bf16x8*)(As[cur] + ar * 32 + (g ^ ((ar >> 1) & 3)) * 8);
    }
#pragma unroll
    for (int n = 0; n < 4; ++n) {
      int br = wc * 64 + n * 16 + c;
      bfr[n] = *(const bf16x8*)(Bs[cur] + br * 32 + (g ^ ((br >> 1) & 3)) * 8);
    }
#pragma unroll
    for (int m = 0; m < MR; ++m)
#pragma unroll
      for (int n = 0; n < 4; ++n)
        acc[m][n] = __builtin_amdgcn_mfma_f32_16x16x32_bf16(af[m], bfr[n], acc[m][n], 0, 0, 0);
    __syncthreads();
    cur ^= 1;
  }
#undef GSTAGE

#pragma unroll
  for (int m = 0; m < MR; ++m) {
    int grow0 = tm * BM + wr * (MT * 16) + m * 16 + g * 4;
#pragma unroll
    for (int n = 0; n < 4; ++n) {
      int gcol = tn * 128 + wc * 64 + n * 16 + c;
      float bv = bias[gcol];
#pragma unroll
      for (int r = 0; r < 4; ++r) {
        int grow = grow0 + r;
        float v = acc[m][n][r] + bv;
        if (DOGELU) v = fast_gelu(v);
        if (DORES) v += res[(size_t)grow * N + gcol];
        if (OUTMODE == 1)
          ((u16*)Cout)[(size_t)grow * N + gcol] = f2bf(v);
        else
          ((float*)Cout)[(size_t)grow * N + gcol] = v;
      }
    }
  }
}

// ---------------- fused windowed+global attention (R10 body verbatim) ----------------
// 8-wave blocks, QBLK=128, dbuf K/V, no-max exp2 softmax, row-sum via ones-MFMA.
// R12 lesson: per-(kt,r) 64-bit mask words cost MORE VALU than the simple per-element
// test (u64 variable shifts are multi-op) — keep the per-element path.
// launch_bounds (512,3): occupancy is LDS-capped at 3 blocks/CU anyway; relaxed reg cap
// gives the scheduler ILP headroom (cannot introduce spills).
__global__ __launch_bounds__(512, 3) void attn_fwd(const u16* __restrict__ qkv,
                                                   const u16* __restrict__ vt,
                                                   const u64* __restrict__ isgq,
                                                   u16* __restrict__ ctx) {
  __shared__ u16 Ks[2][64 * 64];   // [s][dh], chunk-XOR swizzled by (s&7)
  __shared__ u16 Vs[2][64 * 64];   // [dh][s], chunk-XOR swizzled by (dh&7)
  __shared__ u16 Ps[8][16 * 64];   // per-wave P, [q][s], swizzled by (q&7)
  const int t = threadIdx.x, w = t >> 6, l = t & 63, g = l >> 4, c = l & 15;
  const int bid = xcd_swz(blockIdx.x, 512);
  const int qb = bid & 15, h = (bid >> 4) & 15, b = bid >> 8;
  const int q0 = qb * 128 + w * 16;
  const float C2 = 0.18033688011112042f;  // 0.125 * log2(e)

  bf16x8 aq[2];
#pragma unroll
  for (int kf = 0; kf < 2; ++kf) {
    bf16x8 raw = *(const bf16x8*)(qkv + (size_t)(b * 2048 + q0 + c) * 3072 +
                                  h * 64 + kf * 32 + g * 8);
#pragma unroll
    for (int j = 0; j < 8; ++j) aq[kf][j] = (__bf16)((float)raw[j] * C2);
  }

  const u64 qw = isgq[b * 32 + (q0 >> 6)];
  bool qflag[4];
#pragma unroll
  for (int r = 0; r < 4; ++r) qflag[r] = (qw >> ((q0 & 63) + g * 4 + r)) & 1;

  bf16x8 vone;
#pragma unroll
  for (int j = 0; j < 8; ++j) vone[j] = (__bf16)1.0f;

  int poff[4][4];
#pragma unroll
  for (int n = 0; n < 4; ++n)
#pragma unroll
    for (int r = 0; r < 4; ++r) {
      int qr = g * 4 + r, scol = n * 16 + c;
      poff[n][r] = qr * 128 + ((scol * 2) ^ ((qr & 7) << 4));
    }

  f32x4 o[4], ol;
#pragma unroll
  for (int n = 0; n < 4; ++n) o[n] = (f32x4){0.f, 0.f, 0.f, 0.f};
  ol = (f32x4){0.f, 0.f, 0.f, 0.f};

  const int stR = t >> 3, stC = t & 7;
  const int qa0 = q0 + g * 4;

#define STAGE(buf, kt)                                                                       \
  {                                                                                          \
    int ch_ = stC ^ (stR & 7);                                                               \
    gl_lds16(qkv + (size_t)(b * 2048 + (kt)*64 + stR) * 3072 + 1024 + h * 64 + ch_ * 8,      \
             (u16*)Ks[buf] + stR * 64 + stC * 8);                                            \
    gl_lds16(vt + (size_t)((b * 16 + h) * 64 + stR) * 2048 + (kt)*64 + ch_ * 8,              \
             (u16*)Vs[buf] + stR * 64 + stC * 8);                                            \
  }

  STAGE(0, 0);
  __syncthreads();
  int cur = 0;

  for (int kt = 0; kt < 32; ++kt) {
    if (kt + 1 < 32) STAGE(cur ^ 1, kt + 1);
    const u64 kw = isgq[b * 32 + kt];

    // QK^T: S[16 q][64 k] (already x 0.125*log2e via prescaled Q)
    f32x4 sf[4];
#pragma unroll
    for (int n = 0; n < 4; ++n) sf[n] = (f32x4){0.f, 0.f, 0.f, 0.f};
#pragma unroll
    for (int n = 0; n < 4; ++n) {
      int srw = n * 16 + c;
#pragma unroll
      for (int kf = 0; kf < 2; ++kf) {
        bf16x8 kb = *(const bf16x8*)((const char*)Ks[cur] + srw * 128 +
                                     ((kf * 64 + g * 16) ^ ((srw & 7) << 4)));
        sf[n] = __builtin_amdgcn_mfma_f32_16x16x32_bf16(aq[kf], kb, sf[n], 0, 0, 0);
      }
    }

    // mask + exp2 + store P (bf16) — per-element test (R10 proven form)
#pragma unroll
    for (int n = 0; n < 4; ++n) {
      int kcol = kt * 64 + n * 16 + c;
      bool kfl = (kw >> (n * 16 + c)) & 1;
#pragma unroll
      for (int r = 0; r < 4; ++r) {
        int d = qa0 + r - kcol;
        bool ok = ((unsigned)(d + 256) <= 512u) || qflag[r] || kfl;
        float p = fexp2(ok ? sf[n][r] : -1e30f);
        *(u16*)((char*)Ps[w] + poff[n][r]) = f2bf(p);
      }
    }

    // PV: O += P[16][64] * V[64][64]^T; l += P * ones (same pa fragment)
#pragma unroll
    for (int kf = 0; kf < 2; ++kf) {
      bf16x8 pa = *(const bf16x8*)((const char*)Ps[w] + c * 128 +
                                   ((kf * 64 + g * 16) ^ ((c & 7) << 4)));
#pragma unroll
      for (int n = 0; n < 4; ++n) {
        int dh = n * 16 + c;
        bf16x8 vb = *(const bf16x8*)((const char*)Vs[cur] + dh * 128 +
                                     ((kf * 64 + g * 16) ^ ((dh & 7) << 4)));
        o[n] = __builtin_amdgcn_mfma_f32_16x16x32_bf16(pa, vb, o[n], 0, 0, 0);
      }
      ol = __builtin_amdgcn_mfma_f32_16x16x32_bf16(pa, vone, ol, 0, 0, 0);
    }
    __syncthreads();
    cur ^= 1;
  }
#undef STAGE

#pragma unroll
  for (int r = 0; r < 4; ++r) {
    float inv = 1.0f / ol[r];
    int qg = q0 + g * 4 + r;
#pragma unroll
    for (int n = 0; n < 4; ++n)
      ctx[(size_t)(b * 2048 + qg) * 1024 + h * 64 + n * 16 + c] = f2bf(o[n][r] * inv);
  }
}

// ---------------- launcher ----------------

extern "C" void kernel_launch(void* const* d_in, const int* in_sizes, int n_in,
                              void* d_out, int out_size, void* d_ws, size_t ws_size,
                              hipStream_t stream) {
  (void)in_sizes; (void)n_in; (void)out_size; (void)ws_size;
  const float* x = (const float*)d_in[0];
  const unsigned char* isg = (const unsigned char*)d_in[1];
  const float* Wq = (const float*)d_in[2];
  const float* bq = (const float*)d_in[3];
  const float* Wk = (const float*)d_in[4];
  const float* bk = (const float*)d_in[5];
  const float* Wv = (const float*)d_in[6];
  const float* bv = (const float*)d_in[7];
  const float* Wo = (const float*)d_in[8];
  const float* bo = (const float*)d_in[9];
  const float* ln1g = (const float*)d_in[10];
  const float* ln1b = (const float*)d_in[11];
  const float* ln2g = (const float*)d_in[12];
  const float* ln2b = (const float*)d_in[13];
  const float* W1 = (const float*)d_in[14];
  const float* b1 = (const float*)d_in[15];
  const float* W2 = (const float*)d_in[16];
  const float* b2 = (const float*)d_in[17];

  char* ws = (char*)d_ws;
  u16* wqkvt = (u16*)(ws);                    // [3072][1024] bf16, 6MB (wot follows contiguously)
  u16* wot   = (u16*)(ws + 6 * MBYTE);        // [1024][1024], 2MB
  u16* w1t   = (u16*)(ws + 8 * MBYTE);        // [4096][1024], 8MB
  u16* w2t   = (u16*)(ws + 16 * MBYTE);       // [1024][4096], 8MB
  float* bqkv = (float*)(ws + 24 * MBYTE);    // [3072]
  u64* isgq  = (u64*)(ws + 24 * MBYTE + 65536);  // 64 qwords
  u16* hbuf  = (u16*)(ws + 25 * MBYTE);       // [4096][1024] bf16 (h, then h2)
  u16* qkvb  = (u16*)(ws + 33 * MBYTE);       // [4096][3072] bf16, 24MB
  u16* vtb   = (u16*)(ws + 57 * MBYTE);       // [B*H*64][2048] bf16, 8MB
  u16* ctx   = (u16*)(ws + 65 * MBYTE);       // [4096][1024] bf16, 8MB
  float* x1  = (float*)(ws + 73 * MBYTE);     // [4096][1024] f32, 16MB
  u16* ff1   = (u16*)(ws + 33 * MBYTE);       // [4096][4096] bf16, 32MB (aliases qkv+vt, dead by then)

  prep_small<<<13, 256, 0, stream>>>(isg, isgq, bq, bk, bv, bqkv);
  transpose_all<<<12288, 256, 0, stream>>>(Wq, Wk, Wv, Wo, W1, W2, wqkvt, w1t, w2t);

  layernorm_k<<<4096, 256, 0, stream>>>(x, ln1g, ln1b, hbuf);
  gemm_bt<4, 1, false, false><<<768, 256, 0, stream>>>(hbuf, wqkvt, bqkv, nullptr, qkvb,
                                                       4096, 3072, 1024);
  transpose_v<<<1024, 256, 0, stream>>>(qkvb, vtb);
  attn_fwd<<<512, 512, 0, stream>>>(qkvb, vtb, isgq, ctx);
  gemm_bt<2, 0, false, true><<<512, 256, 0, stream>>>(ctx, wot, bo, x, x1, 4096, 1024, 1024);
  layernorm_k<<<4096, 256, 0, stream>>>(x1, ln2g, ln2b, hbuf);
  gemm_bt<4, 1, true, false><<<1024, 256, 0, stream>>>(hbuf, w1t, b1, nullptr, ff1,
                                                       4096, 4096, 1024);
  gemm_bt<2, 0, false, true><<<512, 256, 0, stream>>>(ff1, w2t, b2, x1, (float*)d_out,
                                                      4096, 1024, 4096);
}

// Round 14
// 263.821 us; speedup vs baseline: 1.0579x; 1.0115x over previous
//
#include <hip/hip_runtime.h>
#include <hip/hip_bf16.h>

// TemporalEncoderLayer: LN1 -> QKV -> windowed+global attention -> Wo+res -> LN2 -> GELU MLP + res
// B=2 S=2048 D=1024 H=16 DH=64 HALF_WIN=256. fp32 I/O, bf16 MFMA compute.
// R14 = R13 + transpose_v fused into QKV GEMM epilogue (V written transposed directly).

typedef __bf16 bf16x8 __attribute__((ext_vector_type(8)));
typedef float f32x4 __attribute__((ext_vector_type(4)));
typedef unsigned short u16;
typedef u16 u16x8 __attribute__((ext_vector_type(8)));
typedef u16 u16x4 __attribute__((ext_vector_type(4)));
typedef unsigned long long u64;

#define MBYTE (1ull << 20)

static __device__ __forceinline__ u16 f2bf(float f) {
  union { __hip_bfloat16 h; u16 u; } cv;
  cv.h = __float2bfloat16(f);
  return cv.u;
}

static __device__ __forceinline__ float fexp2(float x) {
#if __has_builtin(__builtin_amdgcn_exp2f)
  return __builtin_amdgcn_exp2f(x);
#else
  return __expf(x * 0.6931471805599453f);
#endif
}

// tanh-form GELU via exp2 (~11 VALU ops vs ~25-30 for erff; max abs err ~1.5e-3)
static __device__ __forceinline__ float fast_gelu(float v) {
  float u = v * (0.7978845608028654f + 0.035677408136300125f * v * v);
  float e = fexp2(u * 2.885390081777927f);  // exp(2u)
  float th = 1.0f - 2.0f / (e + 1.0f);      // tanh(u)
  return 0.5f * v * (1.0f + th);
}

static __device__ __forceinline__ void gl_lds16(const void* g, void* l) {
  __builtin_amdgcn_global_load_lds((const __attribute__((address_space(1))) unsigned int*)g,
                                   (__attribute__((address_space(3))) unsigned int*)l, 16, 0, 0);
}

// XCD-aware block swizzle (grid % 8 == 0): contiguous tile chunk per XCD L2.
static __device__ __forceinline__ int xcd_swz(int bid, int nwg) {
  return (bid & 7) * (nwg >> 3) + (bid >> 3);
}

// ---------------- small utility kernels ----------------

// blocks 0..11: concat bias (3072 elems). block 12: detect is_global layout + pack bitmask.
__global__ void prep_small(const unsigned char* __restrict__ g, u64* __restrict__ isgq,
                           const float* __restrict__ bq, const float* __restrict__ bk,
                           const float* __restrict__ bv, float* __restrict__ bias) {
  int t = threadIdx.x;
  if (blockIdx.x < 12) {
    int i = blockIdx.x * 256 + t;
    float v = (i < 1024) ? bq[i] : (i < 2048) ? bk[i - 1024] : bv[i - 2048];
    bias[i] = v;
    return;
  }
  unsigned int acc = 0;
  for (int i = t; i < 4096; i += 256)
    if (i & 3) acc |= g[i];
  unsigned long long any = __ballot(acc != 0);
  __shared__ unsigned int r4[4];
  if ((t & 63) == 0) r4[t >> 6] = (any != 0) ? 1u : 0u;
  __syncthreads();
  int isInt = (r4[0] | r4[1] | r4[2] | r4[3]) ? 0 : 1;
  if (t < 64) {
    const int* g32 = (const int*)g;
    u64 w = 0;
    for (int j = 0; j < 64; ++j) {
      int idx = t * 64 + j;
      int v = isInt ? g32[idx] : (int)g[idx];
      w |= (u64)(v != 0 ? 1u : 0u) << j;
    }
    isgq[t] = w;
  }
}

// All 6 weight transposes in one kernel (fp32 [R][C] -> bf16 [C][R]):
// blocks [0,4096): Wq/Wk/Wv/Wo (1024x1024 each) -> wqkvo stacked
// blocks [4096,8192): W1 (1024x4096) -> w1t ; [8192,12288): W2 (4096x1024) -> w2t
__global__ __launch_bounds__(256, 4) void transpose_all(
    const float* __restrict__ s0, const float* __restrict__ s1, const float* __restrict__ s2,
    const float* __restrict__ s3, const float* __restrict__ w1, const float* __restrict__ w2,
    u16* __restrict__ dqkvo, u16* __restrict__ d1, u16* __restrict__ d2) {
  __shared__ float tile[32][33];
  int bid = blockIdx.x;
  const float* src;
  u16* dst;
  int R, C, local;
  if (bid < 4096) {
    int sel = bid >> 10;
    src = (sel == 0) ? s0 : (sel == 1) ? s1 : (sel == 2) ? s2 : s3;
    dst = dqkvo + (size_t)sel * 1024 * 1024;
    R = 1024; C = 1024; local = bid & 1023;
  } else if (bid < 8192) {
    src = w1; dst = d1; R = 1024; C = 4096; local = bid - 4096;
  } else {
    src = w2; dst = d2; R = 4096; C = 1024; local = bid - 8192;
  }
  int nCx = C >> 5;
  int bx = local % nCx, by = local / nCx;
  int tx = threadIdx.x & 31, ty = threadIdx.x >> 5;
#pragma unroll
  for (int i = 0; i < 32; i += 8)
    tile[ty + i][tx] = src[(size_t)(by * 32 + ty + i) * C + bx * 32 + tx];
  __syncthreads();
#pragma unroll
  for (int i = 0; i < 32; i += 8)
    dst[(size_t)(bx * 32 + ty + i) * R + by * 32 + tx] = f2bf(tile[tx][ty + i]);
}

// LayerNorm fp32 [4096][1024] -> bf16 [4096][1024]
__global__ __launch_bounds__(256, 4) void layernorm_k(const float* __restrict__ x,
                                                      const float* __restrict__ gam,
                                                      const float* __restrict__ bet,
                                                      u16* __restrict__ out) {
  int row = blockIdx.x, t = threadIdx.x;
  const float4* xr = (const float4*)(x + (size_t)row * 1024);
  float4 v = xr[t];
  float s = v.x + v.y + v.z + v.w;
  float ss = v.x * v.x + v.y * v.y + v.z * v.z + v.w * v.w;
#pragma unroll
  for (int d = 1; d < 64; d <<= 1) {
    s += __shfl_xor(s, d);
    ss += __shfl_xor(ss, d);
  }
  __shared__ float ps[8];
  int w = t >> 6, l = t & 63;
  if (l == 0) { ps[w] = s; ps[4 + w] = ss; }
  __syncthreads();
  s = ps[0] + ps[1] + ps[2] + ps[3];
  ss = ps[4] + ps[5] + ps[6] + ps[7];
  float mean = s * (1.0f / 1024.0f);
  float var = ss * (1.0f / 1024.0f) - mean * mean;
  float rstd = rsqrtf(var + 1e-5f);
  float4 gv = ((const float4*)gam)[t];
  float4 bv = ((const float4*)bet)[t];
  u16x4 o;
  o[0] = f2bf((v.x - mean) * rstd * gv.x + bv.x);
  o[1] = f2bf((v.y - mean) * rstd * gv.y + bv.y);
  o[2] = f2bf((v.z - mean) * rstd * gv.z + bv.z);
  o[3] = f2bf((v.w - mean) * rstd * gv.w + bv.w);
  *(u16x4*)(out + (size_t)row * 1024 + t * 4) = o;
}

// ---------------- GEMM: C[M][N] = A[M][K](bf16) * Bt[N][K]^T + bias (+gelu) (+res) ----------------
// R8/R10 configuration verbatim (proven best): MT*32 x 128 tile, BK=32, 4 waves 2x2,
// 2-phase dbuf, one __syncthreads per iter; LDS chunk swizzle phys = logical ^ ((row>>1)&3)
// via pre-swizzled global source + linear LDS dest (conflict-free, measured 0).
// R9 lesson: min-waves 5/6 -> VGPR cap ~48 < acc(64) -> scratch spill. Keep (3,4).
// R11 lesson: 256-tile fine-phase (10 barriers/K-tile, 1 blk/CU) loses to this simple form.
// R14: VSPLIT variant for the QKV GEMM — V-range columns (gcol>=2048, i.e. tn>=16,
// block-uniform) are written TRANSPOSED directly to vtb[(b*16+h)*64+dh][s] as u16x4
// (4 consecutive s per thread, same vt row); qkvb V-slice is never written and the
// separate transpose_v kernel is eliminated (-16MB traffic, -1 dispatch).
template <int MT, int OUTMODE, bool DOGELU, bool DORES, bool VSPLIT>
__global__ __launch_bounds__(256, (MT == 4) ? 3 : 4) void gemm_bt(
    const u16* __restrict__ A, const u16* __restrict__ Bt, const float* __restrict__ bias,
    const float* __restrict__ res, void* __restrict__ Cout, u16* __restrict__ vtb,
    int M, int N, int K) {
  constexpr int BM = MT * 32;
  constexpr int MR = MT;
  constexpr int SI = MT / 2;
  __shared__ u16 As[2][BM * 32];
  __shared__ u16 Bs[2][128 * 32];
  const int t = threadIdx.x;
  const int w = t >> 6, l = t & 63, g = l >> 4, c = l & 15;
  const int wr = w >> 1, wc = w & 1;
  const int nTn = N >> 7;
  const int bid = xcd_swz(blockIdx.x, gridDim.x);
  const int tm = bid / nTn, tn = bid % nTn;

  f32x4 acc[MR][4];
#pragma unroll
  for (int m = 0; m < MR; ++m)
#pragma unroll
    for (int n = 0; n < 4; ++n) acc[m][n] = (f32x4){0.f, 0.f, 0.f, 0.f};

  const int srow = t >> 2, schunk = t & 3;

#define GSTAGE(buf, k0)                                                                   \
  {                                                                                       \
    _Pragma("unroll") for (int i = 0; i < SI; ++i) {                                      \
      int r_ = srow + i * 64;                                                             \
      int ch_ = schunk ^ ((r_ >> 1) & 3);                                                 \
      gl_lds16(A + (size_t)(tm * BM + r_) * K + (k0) + ch_ * 8,                           \
               (u16*)As[buf] + r_ * 32 + schunk * 8);                                     \
    }                                                                                     \
    _Pragma("unroll") for (int i = 0; i < 2; ++i) {                                       \
      int r_ = srow + i * 64;                                                             \
      int ch_ = schunk ^ ((r_ >> 1) & 3);                                                 \
      gl_lds16(Bt + (size_t)(tn * 128 + r_) * K + (k0) + ch_ * 8,                         \
               (u16*)Bs[buf] + r_ * 32 + schunk * 8);                                     \
    }                                                                                     \
  }

  const int nt = K >> 5;
  GSTAGE(0, 0);
  __syncthreads();
  int cur = 0;

  for (int it = 0; it < nt; ++it) {
    if (it + 1 < nt) GSTAGE(cur ^ 1, (it + 1) * 32);
    bf16x8 af[MR], bfr[4];
#pragma unroll
    for (int m = 0; m < MR; ++m) {
      int ar = wr * (MT * 16) + m * 16 + c;
      af[m] = *(const bf16x8*)(As[cur] + ar * 32 + (g ^ ((ar >> 1) & 3)) * 8);
    }
#pragma unroll
    for (int n = 0; n < 4; ++n) {
      int br = wc * 64 + n * 16 + c;
      bfr[n] = *(const bf16x8*)(Bs[cur] + br * 32 + (g ^ ((br >> 1) & 3)) * 8);
    }
#pragma unroll
    for (int m = 0; m < MR; ++m)
#pragma unroll
      for (int n = 0; n < 4; ++n)
        acc[m][n] = __builtin_amdgcn_mfma_f32_16x16x32_bf16(af[m], bfr[n], acc[m][n], 0, 0, 0);
    __syncthreads();
    cur ^= 1;
  }
#undef GSTAGE

  const bool vside = VSPLIT && (tn * 128 >= 2048);  // block-uniform (V boundary tile-aligned)
#pragma unroll
  for (int m = 0; m < MR; ++m) {
    int grow0 = tm * BM + wr * (MT * 16) + m * 16 + g * 4;
#pragma unroll
    for (int n = 0; n < 4; ++n) {
      int gcol = tn * 128 + wc * 64 + n * 16 + c;
      float bv = bias[gcol];
      if (VSPLIT && vside) {
        // V fragment -> vtb[(b*16+h)*64+dh][s..s+3] as one u16x4 (s = grow within batch)
        int vc = gcol - 2048;
        int hh = vc >> 6, dh = vc & 63;
        int b_ = grow0 >> 11, s0 = grow0 & 2047;
        u16x4 pv;
#pragma unroll
        for (int r = 0; r < 4; ++r) pv[r] = f2bf(acc[m][n][r] + bv);
        *(u16x4*)(vtb + (size_t)((b_ * 16 + hh) * 64 + dh) * 2048 + s0) = pv;
      } else {
#pragma unroll
        for (int r = 0; r < 4; ++r) {
          int grow = grow0 + r;
          float v = acc[m][n][r] + bv;
          if (DOGELU) v = fast_gelu(v);
          if (DORES) v += res[(size_t)grow * N + gcol];
          if (OUTMODE == 1)
            ((u16*)Cout)[(size_t)grow * N + gcol] = f2bf(v);
          else
            ((float*)Cout)[(size_t)grow * N + gcol] = v;
        }
      }
    }
  }
}

// ---------------- fused windowed+global attention (R13/R10 body verbatim) ----------------
// 8-wave blocks, QBLK=128, dbuf K/V, no-max exp2 softmax, row-sum via ones-MFMA.
// R12 lesson: per-(kt,r) 64-bit mask words cost MORE VALU than the per-element test.
__global__ __launch_bounds__(512, 3) void attn_fwd(const u16* __restrict__ qkv,
                                                   const u16* __restrict__ vt,
                                                   const u64* __restrict__ isgq,
                                                   u16* __restrict__ ctx) {
  __shared__ u16 Ks[2][64 * 64];   // [s][dh], chunk-XOR swizzled by (s&7)
  __shared__ u16 Vs[2][64 * 64];   // [dh][s], chunk-XOR swizzled by (dh&7)
  __shared__ u16 Ps[8][16 * 64];   // per-wave P, [q][s], swizzled by (q&7)
  const int t = threadIdx.x, w = t >> 6, l = t & 63, g = l >> 4, c = l & 15;
  const int bid = xcd_swz(blockIdx.x, 512);
  const int qb = bid & 15, h = (bid >> 4) & 15, b = bid >> 8;
  const int q0 = qb * 128 + w * 16;
  const float C2 = 0.18033688011112042f;  // 0.125 * log2(e)

  bf16x8 aq[2];
#pragma unroll
  for (int kf = 0; kf < 2; ++kf) {
    bf16x8 raw = *(const bf16x8*)(qkv + (size_t)(b * 2048 + q0 + c) * 3072 +
                                  h * 64 + kf * 32 + g * 8);
#pragma unroll
    for (int j = 0; j < 8; ++j) aq[kf][j] = (__bf16)((float)raw[j] * C2);
  }

  const u64 qw = isgq[b * 32 + (q0 >> 6)];
  bool qflag[4];
#pragma unroll
  for (int r = 0; r < 4; ++r) qflag[r] = (qw >> ((q0 & 63) + g * 4 + r)) & 1;

  bf16x8 vone;
#pragma unroll
  for (int j = 0; j < 8; ++j) vone[j] = (__bf16)1.0f;

  int poff[4][4];
#pragma unroll
  for (int n = 0; n < 4; ++n)
#pragma unroll
    for (int r = 0; r < 4; ++r) {
      int qr = g * 4 + r, scol = n * 16 + c;
      poff[n][r] = qr * 128 + ((scol * 2) ^ ((qr & 7) << 4));
    }

  f32x4 o[4], ol;
#pragma unroll
  for (int n = 0; n < 4; ++n) o[n] = (f32x4){0.f, 0.f, 0.f, 0.f};
  ol = (f32x4){0.f, 0.f, 0.f, 0.f};

  const int stR = t >> 3, stC = t & 7;
  const int qa0 = q0 + g * 4;

#define STAGE(buf, kt)                                                                       \
  {                                                                                          \
    int ch_ = stC ^ (stR & 7);                                                               \
    gl_lds16(qkv + (size_t)(b * 2048 + (kt)*64 + stR) * 3072 + 1024 + h * 64 + ch_ * 8,      \
             (u16*)Ks[buf] + stR * 64 + stC * 8);                                            \
    gl_lds16(vt + (size_t)((b * 16 + h) * 64 + stR) * 2048 + (kt)*64 + ch_ * 8,              \
             (u16*)Vs[buf] + stR * 64 + stC * 8);                                            \
  }

  STAGE(0, 0);
  __syncthreads();
  int cur = 0;

  for (int kt = 0; kt < 32; ++kt) {
    if (kt + 1 < 32) STAGE(cur ^ 1, kt + 1);
    const u64 kw = isgq[b * 32 + kt];

    // QK^T: S[16 q][64 k] (already x 0.125*log2e via prescaled Q)
    f32x4 sf[4];
#pragma unroll
    for (int n = 0; n < 4; ++n) sf[n] = (f32x4){0.f, 0.f, 0.f, 0.f};
#pragma unroll
    for (int n = 0; n < 4; ++n) {
      int srw = n * 16 + c;
#pragma unroll
      for (int kf = 0; kf < 2; ++kf) {
        bf16x8 kb = *(const bf16x8*)((const char*)Ks[cur] + srw * 128 +
                                     ((kf * 64 + g * 16) ^ ((srw & 7) << 4)));
        sf[n] = __builtin_amdgcn_mfma_f32_16x16x32_bf16(aq[kf], kb, sf[n], 0, 0, 0);
      }
    }

    // mask + exp2 + store P (bf16) — per-element test (proven form)
#pragma unroll
    for (int n = 0; n < 4; ++n) {
      int kcol = kt * 64 + n * 16 + c;
      bool kfl = (kw >> (n * 16 + c)) & 1;
#pragma unroll
      for (int r = 0; r < 4; ++r) {
        int d = qa0 + r - kcol;
        bool ok = ((unsigned)(d + 256) <= 512u) || qflag[r] || kfl;
        float p = fexp2(ok ? sf[n][r] : -1e30f);
        *(u16*)((char*)Ps[w] + poff[n][r]) = f2bf(p);
      }
    }

    // PV: O += P[16][64] * V[64][64]^T; l += P * ones (same pa fragment)
#pragma unroll
    for (int kf = 0; kf < 2; ++kf) {
      bf16x8 pa = *(const bf16x8*)((const char*)Ps[w] + c * 128 +
                                   ((kf * 64 + g * 16) ^ ((c & 7) << 4)));
#pragma unroll
      for (int n = 0; n < 4; ++n) {
        int dh = n * 16 + c;
        bf16x8 vb = *(const bf16x8*)((const char*)Vs[cur] + dh * 128 +
                                     ((kf * 64 + g * 16) ^ ((dh & 7) << 4)));
        o[n] = __builtin_amdgcn_mfma_f32_16x16x32_bf16(pa, vb, o[n], 0, 0, 0);
      }
      ol = __builtin_amdgcn_mfma_f32_16x16x32_bf16(pa, vone, ol, 0, 0, 0);
    }
    __syncthreads();
    cur ^= 1;
  }
#undef STAGE

#pragma unroll
  for (int r = 0; r < 4; ++r) {
    float inv = 1.0f / ol[r];
    int qg = q0 + g * 4 + r;
#pragma unroll
    for (int n = 0; n < 4; ++n)
      ctx[(size_t)(b * 2048 + qg) * 1024 + h * 64 + n * 16 + c] = f2bf(o[n][r] * inv);
  }
}

// ---------------- launcher ----------------

extern "C" void kernel_launch(void* const* d_in, const int* in_sizes, int n_in,
                              void* d_out, int out_size, void* d_ws, size_t ws_size,
                              hipStream_t stream) {
  (void)in_sizes; (void)n_in; (void)out_size; (void)ws_size;
  const float* x = (const float*)d_in[0];
  const unsigned char* isg = (const unsigned char*)d_in[1];
  const float* Wq = (const float*)d_in[2];
  const float* bq = (const float*)d_in[3];
  const float* Wk = (const float*)d_in[4];
  const float* bk = (const float*)d_in[5];
  const float* Wv = (const float*)d_in[6];
  const float* bv = (const float*)d_in[7];
  const float* Wo = (const float*)d_in[8];
  const float* bo = (const float*)d_in[9];
  const float* ln1g = (const float*)d_in[10];
  const float* ln1b = (const float*)d_in[11];
  const float* ln2g = (const float*)d_in[12];
  const float* ln2b = (const float*)d_in[13];
  const float* W1 = (const float*)d_in[14];
  const float* b1 = (const float*)d_in[15];
  const float* W2 = (const float*)d_in[16];
  const float* b2 = (const float*)d_in[17];

  char* ws = (char*)d_ws;
  u16* wqkvt = (u16*)(ws);                    // [3072][1024] bf16, 6MB (wot follows contiguously)
  u16* wot   = (u16*)(ws + 6 * MBYTE);        // [1024][1024], 2MB
  u16* w1t   = (u16*)(ws + 8 * MBYTE);        // [4096][1024], 8MB
  u16* w2t   = (u16*)(ws + 16 * MBYTE);       // [1024][4096], 8MB
  float* bqkv = (float*)(ws + 24 * MBYTE);    // [3072]
  u64* isgq  = (u64*)(ws + 24 * MBYTE + 65536);  // 64 qwords
  u16* hbuf  = (u16*)(ws + 25 * MBYTE);       // [4096][1024] bf16 (h, then h2)
  u16* qkvb  = (u16*)(ws + 33 * MBYTE);       // [4096][3072] bf16, 24MB (V slice unused)
  u16* vtb   = (u16*)(ws + 57 * MBYTE);       // [B*H*64][2048] bf16, 8MB
  u16* ctx   = (u16*)(ws + 65 * MBYTE);       // [4096][1024] bf16, 8MB
  float* x1  = (float*)(ws + 73 * MBYTE);     // [4096][1024] f32, 16MB
  u16* ff1   = (u16*)(ws + 33 * MBYTE);       // [4096][4096] bf16, 32MB (aliases qkv+vt, dead by then)

  prep_small<<<13, 256, 0, stream>>>(isg, isgq, bq, bk, bv, bqkv);
  transpose_all<<<12288, 256, 0, stream>>>(Wq, Wk, Wv, Wo, W1, W2, wqkvt, w1t, w2t);

  layernorm_k<<<4096, 256, 0, stream>>>(x, ln1g, ln1b, hbuf);
  gemm_bt<4, 1, false, false, true><<<768, 256, 0, stream>>>(hbuf, wqkvt, bqkv, nullptr,
                                                             qkvb, vtb, 4096, 3072, 1024);
  attn_fwd<<<512, 512, 0, stream>>>(qkvb, vtb, isgq, ctx);
  gemm_bt<2, 0, false, true, false><<<512, 256, 0, stream>>>(ctx, wot, bo, x, x1, nullptr,
                                                             4096, 1024, 1024);
  layernorm_k<<<4096, 256, 0, stream>>>(x1, ln2g, ln2b, hbuf);
  gemm_bt<4, 1, true, false, false><<<1024, 256, 0, stream>>>(hbuf, w1t, b1, nullptr, ff1,
                                                              nullptr, 4096, 4096, 1024);
  gemm_bt<2, 0, false, true, false><<<512, 256, 0, stream>>>(ff1, w2t, b2, x1, (float*)d_out,
                                                             nullptr, 4096, 1024, 4096);
}

// Round 15
// 255.227 us; speedup vs baseline: 1.0936x; 1.0337x over previous
//
#include <hip/hip_runtime.h>
#include <hip/hip_bf16.h>

// TemporalEncoderLayer: LN1 -> QKV -> windowed+global attention -> Wo+res -> LN2 -> GELU MLP + res
// B=2 S=2048 D=1024 H=16 DH=64 HALF_WIN=256. fp32 I/O, bf16 MFMA compute.
// R15 = R14 + attn full-window fast path + bf16 residual stream (x1) + prep merged into transpose.

typedef __bf16 bf16x8 __attribute__((ext_vector_type(8)));
typedef float f32x4 __attribute__((ext_vector_type(4)));
typedef unsigned short u16;
typedef u16 u16x8 __attribute__((ext_vector_type(8)));
typedef u16 u16x4 __attribute__((ext_vector_type(4)));
typedef unsigned long long u64;

#define MBYTE (1ull << 20)

static __device__ __forceinline__ u16 f2bf(float f) {
  union { __hip_bfloat16 h; u16 u; } cv;
  cv.h = __float2bfloat16(f);
  return cv.u;
}

static __device__ __forceinline__ float bf2f(u16 u) {
  return __uint_as_float(((unsigned int)u) << 16);
}

static __device__ __forceinline__ float fexp2(float x) {
#if __has_builtin(__builtin_amdgcn_exp2f)
  return __builtin_amdgcn_exp2f(x);
#else
  return __expf(x * 0.6931471805599453f);
#endif
}

// tanh-form GELU via exp2 (~11 VALU ops vs ~25-30 for erff; max abs err ~1.5e-3)
static __device__ __forceinline__ float fast_gelu(float v) {
  float u = v * (0.7978845608028654f + 0.035677408136300125f * v * v);
  float e = fexp2(u * 2.885390081777927f);  // exp(2u)
  float th = 1.0f - 2.0f / (e + 1.0f);      // tanh(u)
  return 0.5f * v * (1.0f + th);
}

static __device__ __forceinline__ void gl_lds16(const void* g, void* l) {
  __builtin_amdgcn_global_load_lds((const __attribute__((address_space(1))) unsigned int*)g,
                                   (__attribute__((address_space(3))) unsigned int*)l, 16, 0, 0);
}

// XCD-aware block swizzle (grid % 8 == 0): contiguous tile chunk per XCD L2.
static __device__ __forceinline__ int xcd_swz(int bid, int nwg) {
  return (bid & 7) * (nwg >> 3) + (bid >> 3);
}

// ---------------- prep + weight transposes, one kernel ----------------
// blocks [0,4096): Wq/Wk/Wv/Wo (1024x1024 each) -> wqkvo stacked
// blocks [4096,8192): W1 (1024x4096) -> w1t ; [8192,12288): W2 (4096x1024) -> w2t
// blocks [12288,12300): concat bias ; block 12300: is_global layout-detect + bitmask pack
__global__ __launch_bounds__(256, 4) void transpose_all(
    const float* __restrict__ s0, const float* __restrict__ s1, const float* __restrict__ s2,
    const float* __restrict__ s3, const float* __restrict__ w1, const float* __restrict__ w2,
    u16* __restrict__ dqkvo, u16* __restrict__ d1, u16* __restrict__ d2,
    const unsigned char* __restrict__ g, u64* __restrict__ isgq,
    const float* __restrict__ bq, const float* __restrict__ bk,
    const float* __restrict__ bv, float* __restrict__ bias) {
  int bid = blockIdx.x;
  int t = threadIdx.x;
  if (bid >= 12288) {
    int local = bid - 12288;
    if (local < 12) {
      int i = local * 256 + t;
      float v = (i < 1024) ? bq[i] : (i < 2048) ? bk[i - 1024] : bv[i - 2048];
      bias[i] = v;
      return;
    }
    unsigned int acc = 0;
    for (int i = t; i < 4096; i += 256)
      if (i & 3) acc |= g[i];
    unsigned long long any = __ballot(acc != 0);
    __shared__ unsigned int r4[4];
    if ((t & 63) == 0) r4[t >> 6] = (any != 0) ? 1u : 0u;
    __syncthreads();
    int isInt = (r4[0] | r4[1] | r4[2] | r4[3]) ? 0 : 1;
    if (t < 64) {
      const int* g32 = (const int*)g;
      u64 w = 0;
      for (int j = 0; j < 64; ++j) {
        int idx = t * 64 + j;
        int v = isInt ? g32[idx] : (int)g[idx];
        w |= (u64)(v != 0 ? 1u : 0u) << j;
      }
      isgq[t] = w;
    }
    return;
  }
  __shared__ float tile[32][33];
  const float* src;
  u16* dst;
  int R, C, local;
  if (bid < 4096) {
    int sel = bid >> 10;
    src = (sel == 0) ? s0 : (sel == 1) ? s1 : (sel == 2) ? s2 : s3;
    dst = dqkvo + (size_t)sel * 1024 * 1024;
    R = 1024; C = 1024; local = bid & 1023;
  } else if (bid < 8192) {
    src = w1; dst = d1; R = 1024; C = 4096; local = bid - 4096;
  } else {
    src = w2; dst = d2; R = 4096; C = 1024; local = bid - 8192;
  }
  int nCx = C >> 5;
  int bx = local % nCx, by = local / nCx;
  int tx = t & 31, ty = t >> 5;
#pragma unroll
  for (int i = 0; i < 32; i += 8)
    tile[ty + i][tx] = src[(size_t)(by * 32 + ty + i) * C + bx * 32 + tx];
  __syncthreads();
#pragma unroll
  for (int i = 0; i < 32; i += 8)
    dst[(size_t)(bx * 32 + ty + i) * R + by * 32 + tx] = f2bf(tile[tx][ty + i]);
}

// LayerNorm [4096][1024] -> bf16 [4096][1024]; input fp32 (BFIN=false) or bf16 (BFIN=true)
template <bool BFIN>
__global__ __launch_bounds__(256, 4) void layernorm_k(const void* __restrict__ xin,
                                                      const float* __restrict__ gam,
                                                      const float* __restrict__ bet,
                                                      u16* __restrict__ out) {
  int row = blockIdx.x, t = threadIdx.x;
  float4 v;
  if (BFIN) {
    u16x4 raw = ((const u16x4*)((const u16*)xin + (size_t)row * 1024))[t];
    v.x = bf2f(raw[0]); v.y = bf2f(raw[1]); v.z = bf2f(raw[2]); v.w = bf2f(raw[3]);
  } else {
    v = ((const float4*)((const float*)xin + (size_t)row * 1024))[t];
  }
  float s = v.x + v.y + v.z + v.w;
  float ss = v.x * v.x + v.y * v.y + v.z * v.z + v.w * v.w;
#pragma unroll
  for (int d = 1; d < 64; d <<= 1) {
    s += __shfl_xor(s, d);
    ss += __shfl_xor(ss, d);
  }
  __shared__ float ps[8];
  int w = t >> 6, l = t & 63;
  if (l == 0) { ps[w] = s; ps[4 + w] = ss; }
  __syncthreads();
  s = ps[0] + ps[1] + ps[2] + ps[3];
  ss = ps[4] + ps[5] + ps[6] + ps[7];
  float mean = s * (1.0f / 1024.0f);
  float var = ss * (1.0f / 1024.0f) - mean * mean;
  float rstd = rsqrtf(var + 1e-5f);
  float4 gv = ((const float4*)gam)[t];
  float4 bv = ((const float4*)bet)[t];
  u16x4 o;
  o[0] = f2bf((v.x - mean) * rstd * gv.x + bv.x);
  o[1] = f2bf((v.y - mean) * rstd * gv.y + bv.y);
  o[2] = f2bf((v.z - mean) * rstd * gv.z + bv.z);
  o[3] = f2bf((v.w - mean) * rstd * gv.w + bv.w);
  *(u16x4*)(out + (size_t)row * 1024 + t * 4) = o;
}

// ---------------- GEMM: C[M][N] = A[M][K](bf16) * Bt[N][K]^T + bias (+gelu) (+res) ----------------
// R8/R10 configuration verbatim (proven best): MT*32 x 128 tile, BK=32, 4 waves 2x2,
// 2-phase dbuf, one __syncthreads per iter; LDS chunk swizzle phys = logical ^ ((row>>1)&3)
// via pre-swizzled global source + linear LDS dest (conflict-free, measured 0).
// R9 lesson: min-waves 5/6 -> VGPR cap ~48 < acc(64) -> scratch spill. Keep (3,4).
// R11 lesson: 256-tile fine-phase loses to this simple form.
// RESMODE: 0 none, 1 fp32 residual, 2 bf16 residual. VSPLIT: QKV's V-slice written
// transposed directly to vtb (R14, proven).
template <int MT, int OUTMODE, bool DOGELU, int RESMODE, bool VSPLIT>
__global__ __launch_bounds__(256, (MT == 4) ? 3 : 4) void gemm_bt(
    const u16* __restrict__ A, const u16* __restrict__ Bt, const float* __restrict__ bias,
    const void* __restrict__ res, void* __restrict__ Cout, u16* __restrict__ vtb,
    int M, int N, int K) {
  constexpr int BM = MT * 32;
  constexpr int MR = MT;
  constexpr int SI = MT / 2;
  __shared__ u16 As[2][BM * 32];
  __shared__ u16 Bs[2][128 * 32];
  const int t = threadIdx.x;
  const int w = t >> 6, l = t & 63, g = l >> 4, c = l & 15;
  const int wr = w >> 1, wc = w & 1;
  const int nTn = N >> 7;
  const int bid = xcd_swz(blockIdx.x, gridDim.x);
  const int tm = bid / nTn, tn = bid % nTn;

  f32x4 acc[MR][4];
#pragma unroll
  for (int m = 0; m < MR; ++m)
#pragma unroll
    for (int n = 0; n < 4; ++n) acc[m][n] = (f32x4){0.f, 0.f, 0.f, 0.f};

  const int srow = t >> 2, schunk = t & 3;

#define GSTAGE(buf, k0)                                                                   \
  {                                                                                       \
    _Pragma("unroll") for (int i = 0; i < SI; ++i) {                                      \
      int r_ = srow + i * 64;                                                             \
      int ch_ = schunk ^ ((r_ >> 1) & 3);                                                 \
      gl_lds16(A + (size_t)(tm * BM + r_) * K + (k0) + ch_ * 8,                           \
               (u16*)As[buf] + r_ * 32 + schunk * 8);                                     \
    }                                                                                     \
    _Pragma("unroll") for (int i = 0; i < 2; ++i) {                                       \
      int r_ = srow + i * 64;                                                             \
      int ch_ = schunk ^ ((r_ >> 1) & 3);                                                 \
      gl_lds16(Bt + (size_t)(tn * 128 + r_) * K + (k0) + ch_ * 8,                         \
               (u16*)Bs[buf] + r_ * 32 + schunk * 8);                                     \
    }                                                                                     \
  }

  const int nt = K >> 5;
  GSTAGE(0, 0);
  __syncthreads();
  int cur = 0;

  for (int it = 0; it < nt; ++it) {
    if (it + 1 < nt) GSTAGE(cur ^ 1, (it + 1) * 32);
    bf16x8 af[MR], bfr[4];
#pragma unroll
    for (int m = 0; m < MR; ++m) {
      int ar = wr * (MT * 16) + m * 16 + c;
      af[m] = *(const bf16x8*)(As[cur] + ar * 32 + (g ^ ((ar >> 1) & 3)) * 8);
    }
#pragma unroll
    for (int n = 0; n < 4; ++n) {
      int br = wc * 64 + n * 16 + c;
      bfr[n] = *(const bf16x8*)(Bs[cur] + br * 32 + (g ^ ((br >> 1) & 3)) * 8);
    }
#pragma unroll
    for (int m = 0; m < MR; ++m)
#pragma unroll
      for (int n = 0; n < 4; ++n)
        acc[m][n] = __builtin_amdgcn_mfma_f32_16x16x32_bf16(af[m], bfr[n], acc[m][n], 0, 0, 0);
    __syncthreads();
    cur ^= 1;
  }
#undef GSTAGE

  const bool vside = VSPLIT && (tn * 128 >= 2048);  // block-uniform (V boundary tile-aligned)
#pragma unroll
  for (int m = 0; m < MR; ++m) {
    int grow0 = tm * BM + wr * (MT * 16) + m * 16 + g * 4;
#pragma unroll
    for (int n = 0; n < 4; ++n) {
      int gcol = tn * 128 + wc * 64 + n * 16 + c;
      float bv = bias[gcol];
      if (VSPLIT && vside) {
        // V fragment -> vtb[(b*16+h)*64+dh][s..s+3] as one u16x4 (s = grow within batch)
        int vc = gcol - 2048;
        int hh = vc >> 6, dh = vc & 63;
        int b_ = grow0 >> 11, s0 = grow0 & 2047;
        u16x4 pv;
#pragma unroll
        for (int r = 0; r < 4; ++r) pv[r] = f2bf(acc[m][n][r] + bv);
        *(u16x4*)(vtb + (size_t)((b_ * 16 + hh) * 64 + dh) * 2048 + s0) = pv;
      } else {
#pragma unroll
        for (int r = 0; r < 4; ++r) {
          int grow = grow0 + r;
          float v = acc[m][n][r] + bv;
          if (DOGELU) v = fast_gelu(v);
          if (RESMODE == 1) v += ((const float*)res)[(size_t)grow * N + gcol];
          if (RESMODE == 2) v += bf2f(((const u16*)res)[(size_t)grow * N + gcol]);
          if (OUTMODE == 1)
            ((u16*)Cout)[(size_t)grow * N + gcol] = f2bf(v);
          else
            ((float*)Cout)[(size_t)grow * N + gcol] = v;
        }
      }
    }
  }
}

// ---------------- fused windowed+global attention ----------------
// R13/R10 body + R15 full-window fast path: tiles with q0-241 <= kt*64 <= q0+193 have
// ALL (q,k) pairs in-window for this wave's 16 q-rows (mask is an OR -> globals
// irrelevant) — wave-uniform branch skips the entire mask computation (~7/32 tiles).
__global__ __launch_bounds__(512, 3) void attn_fwd(const u16* __restrict__ qkv,
                                                   const u16* __restrict__ vt,
                                                   const u64* __restrict__ isgq,
                                                   u16* __restrict__ ctx) {
  __shared__ u16 Ks[2][64 * 64];   // [s][dh], chunk-XOR swizzled by (s&7)
  __shared__ u16 Vs[2][64 * 64];   // [dh][s], chunk-XOR swizzled by (dh&7)
  __shared__ u16 Ps[8][16 * 64];   // per-wave P, [q][s], swizzled by (q&7)
  const int t = threadIdx.x, w = t >> 6, l = t & 63, g = l >> 4, c = l & 15;
  const int bid = xcd_swz(blockIdx.x, 512);
  const int qb = bid & 15, h = (bid >> 4) & 15, b = bid >> 8;
  const int q0 = qb * 128 + w * 16;
  const float C2 = 0.18033688011112042f;  // 0.125 * log2(e)

  bf16x8 aq[2];
#pragma unroll
  for (int kf = 0; kf < 2; ++kf) {
    bf16x8 raw = *(const bf16x8*)(qkv + (size_t)(b * 2048 + q0 + c) * 3072 +
                                  h * 64 + kf * 32 + g * 8);
#pragma unroll
    for (int j = 0; j < 8; ++j) aq[kf][j] = (__bf16)((float)raw[j] * C2);
  }

  const u64 qw = isgq[b * 32 + (q0 >> 6)];
  bool qflag[4];
#pragma unroll
  for (int r = 0; r < 4; ++r) qflag[r] = (qw >> ((q0 & 63) + g * 4 + r)) & 1;

  bf16x8 vone;
#pragma unroll
  for (int j = 0; j < 8; ++j) vone[j] = (__bf16)1.0f;

  int poff[4][4];
#pragma unroll
  for (int n = 0; n < 4; ++n)
#pragma unroll
    for (int r = 0; r < 4; ++r) {
      int qr = g * 4 + r, scol = n * 16 + c;
      poff[n][r] = qr * 128 + ((scol * 2) ^ ((qr & 7) << 4));
    }

  f32x4 o[4], ol;
#pragma unroll
  for (int n = 0; n < 4; ++n) o[n] = (f32x4){0.f, 0.f, 0.f, 0.f};
  ol = (f32x4){0.f, 0.f, 0.f, 0.f};

  const int stR = t >> 3, stC = t & 7;
  const int qa0 = q0 + g * 4;

#define STAGE(buf, kt)                                                                       \
  {                                                                                          \
    int ch_ = stC ^ (stR & 7);                                                               \
    gl_lds16(qkv + (size_t)(b * 2048 + (kt)*64 + stR) * 3072 + 1024 + h * 64 + ch_ * 8,      \
             (u16*)Ks[buf] + stR * 64 + stC * 8);                                            \
    gl_lds16(vt + (size_t)((b * 16 + h) * 64 + stR) * 2048 + (kt)*64 + ch_ * 8,              \
             (u16*)Vs[buf] + stR * 64 + stC * 8);                                            \
  }

  STAGE(0, 0);
  __syncthreads();
  int cur = 0;

  for (int kt = 0; kt < 32; ++kt) {
    if (kt + 1 < 32) STAGE(cur ^ 1, kt + 1);
    const u64 kw = isgq[b * 32 + kt];

    // QK^T: S[16 q][64 k] (already x 0.125*log2e via prescaled Q)
    f32x4 sf[4];
#pragma unroll
    for (int n = 0; n < 4; ++n) sf[n] = (f32x4){0.f, 0.f, 0.f, 0.f};
#pragma unroll
    for (int n = 0; n < 4; ++n) {
      int srw = n * 16 + c;
#pragma unroll
      for (int kf = 0; kf < 2; ++kf) {
        bf16x8 kb = *(const bf16x8*)((const char*)Ks[cur] + srw * 128 +
                                     ((kf * 64 + g * 16) ^ ((srw & 7) << 4)));
        sf[n] = __builtin_amdgcn_mfma_f32_16x16x32_bf16(aq[kf], kb, sf[n], 0, 0, 0);
      }
    }

    // softmax numerator: fast path when whole tile in-window for this wave's 16 rows
    const int k64 = kt * 64;
    if (k64 >= q0 - 241 && k64 <= q0 + 193) {
#pragma unroll
      for (int n = 0; n < 4; ++n)
#pragma unroll
        for (int r = 0; r < 4; ++r)
          *(u16*)((char*)Ps[w] + poff[n][r]) = f2bf(fexp2(sf[n][r]));
    } else {
#pragma unroll
      for (int n = 0; n < 4; ++n) {
        int kcol = k64 + n * 16 + c;
        bool kfl = (kw >> (n * 16 + c)) & 1;
#pragma unroll
        for (int r = 0; r < 4; ++r) {
          int d = qa0 + r - kcol;
          bool ok = ((unsigned)(d + 256) <= 512u) || qflag[r] || kfl;
          float p = fexp2(ok ? sf[n][r] : -1e30f);
          *(u16*)((char*)Ps[w] + poff[n][r]) = f2bf(p);
        }
      }
    }

    // PV: O += P[16][64] * V[64][64]^T; l += P * ones (same pa fragment)
#pragma unroll
    for (int kf = 0; kf < 2; ++kf) {
      bf16x8 pa = *(const bf16x8*)((const char*)Ps[w] + c * 128 +
                                   ((kf * 64 + g * 16) ^ ((c & 7) << 4)));
#pragma unroll
      for (int n = 0; n < 4; ++n) {
        int dh = n * 16 + c;
        bf16x8 vb = *(const bf16x8*)((const char*)Vs[cur] + dh * 128 +
                                     ((kf * 64 + g * 16) ^ ((dh & 7) << 4)));
        o[n] = __builtin_amdgcn_mfma_f32_16x16x32_bf16(pa, vb, o[n], 0, 0, 0);
      }
      ol = __builtin_amdgcn_mfma_f32_16x16x32_bf16(pa, vone, ol, 0, 0, 0);
    }
    __syncthreads();
    cur ^= 1;
  }
#undef STAGE

#pragma unroll
  for (int r = 0; r < 4; ++r) {
    float inv = 1.0f / ol[r];
    int qg = q0 + g * 4 + r;
#pragma unroll
    for (int n = 0; n < 4; ++n)
      ctx[(size_t)(b * 2048 + qg) * 1024 + h * 64 + n * 16 + c] = f2bf(o[n][r] * inv);
  }
}

// ---------------- launcher ----------------

extern "C" void kernel_launch(void* const* d_in, const int* in_sizes, int n_in,
                              void* d_out, int out_size, void* d_ws, size_t ws_size,
                              hipStream_t stream) {
  (void)in_sizes; (void)n_in; (void)out_size; (void)ws_size;
  const float* x = (const float*)d_in[0];
  const unsigned char* isg = (const unsigned char*)d_in[1];
  const float* Wq = (const float*)d_in[2];
  const float* bq = (const float*)d_in[3];
  const float* Wk = (const float*)d_in[4];
  const float* bk = (const float*)d_in[5];
  const float* Wv = (const float*)d_in[6];
  const float* bv = (const float*)d_in[7];
  const float* Wo = (const float*)d_in[8];
  const float* bo = (const float*)d_in[9];
  const float* ln1g = (const float*)d_in[10];
  const float* ln1b = (const float*)d_in[11];
  const float* ln2g = (const float*)d_in[12];
  const float* ln2b = (const float*)d_in[13];
  const float* W1 = (const float*)d_in[14];
  const float* b1 = (const float*)d_in[15];
  const float* W2 = (const float*)d_in[16];
  const float* b2 = (const float*)d_in[17];

  char* ws = (char*)d_ws;
  u16* wqkvt = (u16*)(ws);                    // [3072][1024] bf16, 6MB (wot follows contiguously)
  u16* wot   = (u16*)(ws + 6 * MBYTE);        // [1024][1024], 2MB
  u16* w1t   = (u16*)(ws + 8 * MBYTE);        // [4096][1024], 8MB
  u16* w2t   = (u16*)(ws + 16 * MBYTE);       // [1024][4096], 8MB
  float* bqkv = (float*)(ws + 24 * MBYTE);    // [3072]
  u64* isgq  = (u64*)(ws + 24 * MBYTE + 65536);  // 64 qwords
  u16* hbuf  = (u16*)(ws + 25 * MBYTE);       // [4096][1024] bf16 (h, then h2)
  u16* qkvb  = (u16*)(ws + 33 * MBYTE);       // [4096][3072] bf16, 24MB (V slice unused)
  u16* vtb   = (u16*)(ws + 57 * MBYTE);       // [B*H*64][2048] bf16, 8MB
  u16* ctx   = (u16*)(ws + 65 * MBYTE);       // [4096][1024] bf16, 8MB
  u16* x1b   = (u16*)(ws + 73 * MBYTE);       // [4096][1024] bf16 residual stream, 8MB
  u16* ff1   = (u16*)(ws + 33 * MBYTE);       // [4096][4096] bf16, 32MB (aliases qkv+vt, dead by then)

  transpose_all<<<12301, 256, 0, stream>>>(Wq, Wk, Wv, Wo, W1, W2, wqkvt, w1t, w2t,
                                           isg, isgq, bq, bk, bv, bqkv);

  layernorm_k<false><<<4096, 256, 0, stream>>>(x, ln1g, ln1b, hbuf);
  gemm_bt<4, 1, false, 0, true><<<768, 256, 0, stream>>>(hbuf, wqkvt, bqkv, nullptr,
                                                         qkvb, vtb, 4096, 3072, 1024);
  attn_fwd<<<512, 512, 0, stream>>>(qkvb, vtb, isgq, ctx);
  gemm_bt<2, 1, false, 1, false><<<512, 256, 0, stream>>>(ctx, wot, bo, x, x1b, nullptr,
                                                          4096, 1024, 1024);
  layernorm_k<true><<<4096, 256, 0, stream>>>(x1b, ln2g, ln2b, hbuf);
  gemm_bt<4, 1, true, 0, false><<<1024, 256, 0, stream>>>(hbuf, w1t, b1, nullptr, ff1,
                                                          nullptr, 4096, 4096, 1024);
  gemm_bt<2, 0, false, 2, false><<<512, 256, 0, stream>>>(ff1, w2t, b2, x1b, (float*)d_out,
                                                          nullptr, 4096, 1024, 4096);
}

// Round 16
// 249.254 us; speedup vs baseline: 1.1198x; 1.0240x over previous
//
#include <hip/hip_runtime.h>
#include <hip/hip_bf16.h>

// TemporalEncoderLayer: LN1 -> QKV -> windowed+global attention -> Wo+res -> LN2 -> GELU MLP + res
// B=2 S=2048 D=1024 H=16 DH=64 HALF_WIN=256. fp32 I/O, bf16 MFMA compute.
// R16 = R15 + dedicated W2 GEMM with BK=64 (halves the 128-iteration barrier overhead).

typedef __bf16 bf16x8 __attribute__((ext_vector_type(8)));
typedef float f32x4 __attribute__((ext_vector_type(4)));
typedef unsigned short u16;
typedef u16 u16x8 __attribute__((ext_vector_type(8)));
typedef u16 u16x4 __attribute__((ext_vector_type(4)));
typedef unsigned long long u64;

#define MBYTE (1ull << 20)

static __device__ __forceinline__ u16 f2bf(float f) {
  union { __hip_bfloat16 h; u16 u; } cv;
  cv.h = __float2bfloat16(f);
  return cv.u;
}

static __device__ __forceinline__ float bf2f(u16 u) {
  return __uint_as_float(((unsigned int)u) << 16);
}

static __device__ __forceinline__ float fexp2(float x) {
#if __has_builtin(__builtin_amdgcn_exp2f)
  return __builtin_amdgcn_exp2f(x);
#else
  return __expf(x * 0.6931471805599453f);
#endif
}

// tanh-form GELU via exp2 (~11 VALU ops vs ~25-30 for erff; max abs err ~1.5e-3)
static __device__ __forceinline__ float fast_gelu(float v) {
  float u = v * (0.7978845608028654f + 0.035677408136300125f * v * v);
  float e = fexp2(u * 2.885390081777927f);  // exp(2u)
  float th = 1.0f - 2.0f / (e + 1.0f);      // tanh(u)
  return 0.5f * v * (1.0f + th);
}

static __device__ __forceinline__ void gl_lds16(const void* g, void* l) {
  __builtin_amdgcn_global_load_lds((const __attribute__((address_space(1))) unsigned int*)g,
                                   (__attribute__((address_space(3))) unsigned int*)l, 16, 0, 0);
}

// XCD-aware block swizzle (grid % 8 == 0): contiguous tile chunk per XCD L2.
static __device__ __forceinline__ int xcd_swz(int bid, int nwg) {
  return (bid & 7) * (nwg >> 3) + (bid >> 3);
}

// ---------------- prep + weight transposes, one kernel ----------------
__global__ __launch_bounds__(256, 4) void transpose_all(
    const float* __restrict__ s0, const float* __restrict__ s1, const float* __restrict__ s2,
    const float* __restrict__ s3, const float* __restrict__ w1, const float* __restrict__ w2,
    u16* __restrict__ dqkvo, u16* __restrict__ d1, u16* __restrict__ d2,
    const unsigned char* __restrict__ g, u64* __restrict__ isgq,
    const float* __restrict__ bq, const float* __restrict__ bk,
    const float* __restrict__ bv, float* __restrict__ bias) {
  int bid = blockIdx.x;
  int t = threadIdx.x;
  if (bid >= 12288) {
    int local = bid - 12288;
    if (local < 12) {
      int i = local * 256 + t;
      float v = (i < 1024) ? bq[i] : (i < 2048) ? bk[i - 1024] : bv[i - 2048];
      bias[i] = v;
      return;
    }
    unsigned int acc = 0;
    for (int i = t; i < 4096; i += 256)
      if (i & 3) acc |= g[i];
    unsigned long long any = __ballot(acc != 0);
    __shared__ unsigned int r4[4];
    if ((t & 63) == 0) r4[t >> 6] = (any != 0) ? 1u : 0u;
    __syncthreads();
    int isInt = (r4[0] | r4[1] | r4[2] | r4[3]) ? 0 : 1;
    if (t < 64) {
      const int* g32 = (const int*)g;
      u64 w = 0;
      for (int j = 0; j < 64; ++j) {
        int idx = t * 64 + j;
        int v = isInt ? g32[idx] : (int)g[idx];
        w |= (u64)(v != 0 ? 1u : 0u) << j;
      }
      isgq[t] = w;
    }
    return;
  }
  __shared__ float tile[32][33];
  const float* src;
  u16* dst;
  int R, C, local;
  if (bid < 4096) {
    int sel = bid >> 10;
    src = (sel == 0) ? s0 : (sel == 1) ? s1 : (sel == 2) ? s2 : s3;
    dst = dqkvo + (size_t)sel * 1024 * 1024;
    R = 1024; C = 1024; local = bid & 1023;
  } else if (bid < 8192) {
    src = w1; dst = d1; R = 1024; C = 4096; local = bid - 4096;
  } else {
    src = w2; dst = d2; R = 4096; C = 1024; local = bid - 8192;
  }
  int nCx = C >> 5;
  int bx = local % nCx, by = local / nCx;
  int tx = t & 31, ty = t >> 5;
#pragma unroll
  for (int i = 0; i < 32; i += 8)
    tile[ty + i][tx] = src[(size_t)(by * 32 + ty + i) * C + bx * 32 + tx];
  __syncthreads();
#pragma unroll
  for (int i = 0; i < 32; i += 8)
    dst[(size_t)(bx * 32 + ty + i) * R + by * 32 + tx] = f2bf(tile[tx][ty + i]);
}

// LayerNorm [4096][1024] -> bf16 [4096][1024]; input fp32 (BFIN=false) or bf16 (BFIN=true)
template <bool BFIN>
__global__ __launch_bounds__(256, 4) void layernorm_k(const void* __restrict__ xin,
                                                      const float* __restrict__ gam,
                                                      const float* __restrict__ bet,
                                                      u16* __restrict__ out) {
  int row = blockIdx.x, t = threadIdx.x;
  float4 v;
  if (BFIN) {
    u16x4 raw = ((const u16x4*)((const u16*)xin + (size_t)row * 1024))[t];
    v.x = bf2f(raw[0]); v.y = bf2f(raw[1]); v.z = bf2f(raw[2]); v.w = bf2f(raw[3]);
  } else {
    v = ((const float4*)((const float*)xin + (size_t)row * 1024))[t];
  }
  float s = v.x + v.y + v.z + v.w;
  float ss = v.x * v.x + v.y * v.y + v.z * v.z + v.w * v.w;
#pragma unroll
  for (int d = 1; d < 64; d <<= 1) {
    s += __shfl_xor(s, d);
    ss += __shfl_xor(ss, d);
  }
  __shared__ float ps[8];
  int w = t >> 6, l = t & 63;
  if (l == 0) { ps[w] = s; ps[4 + w] = ss; }
  __syncthreads();
  s = ps[0] + ps[1] + ps[2] + ps[3];
  ss = ps[4] + ps[5] + ps[6] + ps[7];
  float mean = s * (1.0f / 1024.0f);
  float var = ss * (1.0f / 1024.0f) - mean * mean;
  float rstd = rsqrtf(var + 1e-5f);
  float4 gv = ((const float4*)gam)[t];
  float4 bv = ((const float4*)bet)[t];
  u16x4 o;
  o[0] = f2bf((v.x - mean) * rstd * gv.x + bv.x);
  o[1] = f2bf((v.y - mean) * rstd * gv.y + bv.y);
  o[2] = f2bf((v.z - mean) * rstd * gv.z + bv.z);
  o[3] = f2bf((v.w - mean) * rstd * gv.w + bv.w);
  *(u16x4*)(out + (size_t)row * 1024 + t * 4) = o;
}

// ---------------- GEMM (BK=32 family, proven): C = A*Bt^T + bias (+gelu) (+res) ----------------
// RESMODE: 0 none, 1 fp32 residual, 2 bf16 residual. VSPLIT: QKV V-slice -> vtb transposed.
template <int MT, int OUTMODE, bool DOGELU, int RESMODE, bool VSPLIT>
__global__ __launch_bounds__(256, (MT == 4) ? 3 : 4) void gemm_bt(
    const u16* __restrict__ A, const u16* __restrict__ Bt, const float* __restrict__ bias,
    const void* __restrict__ res, void* __restrict__ Cout, u16* __restrict__ vtb,
    int M, int N, int K) {
  constexpr int BM = MT * 32;
  constexpr int MR = MT;
  constexpr int SI = MT / 2;
  __shared__ u16 As[2][BM * 32];
  __shared__ u16 Bs[2][128 * 32];
  const int t = threadIdx.x;
  const int w = t >> 6, l = t & 63, g = l >> 4, c = l & 15;
  const int wr = w >> 1, wc = w & 1;
  const int nTn = N >> 7;
  const int bid = xcd_swz(blockIdx.x, gridDim.x);
  const int tm = bid / nTn, tn = bid % nTn;

  f32x4 acc[MR][4];
#pragma unroll
  for (int m = 0; m < MR; ++m)
#pragma unroll
    for (int n = 0; n < 4; ++n) acc[m][n] = (f32x4){0.f, 0.f, 0.f, 0.f};

  const int srow = t >> 2, schunk = t & 3;

#define GSTAGE(buf, k0)                                                                   \
  {                                                                                       \
    _Pragma("unroll") for (int i = 0; i < SI; ++i) {                                      \
      int r_ = srow + i * 64;                                                             \
      int ch_ = schunk ^ ((r_ >> 1) & 3);                                                 \
      gl_lds16(A + (size_t)(tm * BM + r_) * K + (k0) + ch_ * 8,                           \
               (u16*)As[buf] + r_ * 32 + schunk * 8);                                     \
    }                                                                                     \
    _Pragma("unroll") for (int i = 0; i < 2; ++i) {                                       \
      int r_ = srow + i * 64;                                                             \
      int ch_ = schunk ^ ((r_ >> 1) & 3);                                                 \
      gl_lds16(Bt + (size_t)(tn * 128 + r_) * K + (k0) + ch_ * 8,                         \
               (u16*)Bs[buf] + r_ * 32 + schunk * 8);                                     \
    }                                                                                     \
  }

  const int nt = K >> 5;
  GSTAGE(0, 0);
  __syncthreads();
  int cur = 0;

  for (int it = 0; it < nt; ++it) {
    if (it + 1 < nt) GSTAGE(cur ^ 1, (it + 1) * 32);
    bf16x8 af[MR], bfr[4];
#pragma unroll
    for (int m = 0; m < MR; ++m) {
      int ar = wr * (MT * 16) + m * 16 + c;
      af[m] = *(const bf16x8*)(As[cur] + ar * 32 + (g ^ ((ar >> 1) & 3)) * 8);
    }
#pragma unroll
    for (int n = 0; n < 4; ++n) {
      int br = wc * 64 + n * 16 + c;
      bfr[n] = *(const bf16x8*)(Bs[cur] + br * 32 + (g ^ ((br >> 1) & 3)) * 8);
    }
#pragma unroll
    for (int m = 0; m < MR; ++m)
#pragma unroll
      for (int n = 0; n < 4; ++n)
        acc[m][n] = __builtin_amdgcn_mfma_f32_16x16x32_bf16(af[m], bfr[n], acc[m][n], 0, 0, 0);
    __syncthreads();
    cur ^= 1;
  }
#undef GSTAGE

  const bool vside = VSPLIT && (tn * 128 >= 2048);  // block-uniform (V boundary tile-aligned)
#pragma unroll
  for (int m = 0; m < MR; ++m) {
    int grow0 = tm * BM + wr * (MT * 16) + m * 16 + g * 4;
#pragma unroll
    for (int n = 0; n < 4; ++n) {
      int gcol = tn * 128 + wc * 64 + n * 16 + c;
      float bv = bias[gcol];
      if (VSPLIT && vside) {
        int vc = gcol - 2048;
        int hh = vc >> 6, dh = vc & 63;
        int b_ = grow0 >> 11, s0 = grow0 & 2047;
        u16x4 pv;
#pragma unroll
        for (int r = 0; r < 4; ++r) pv[r] = f2bf(acc[m][n][r] + bv);
        *(u16x4*)(vtb + (size_t)((b_ * 16 + hh) * 64 + dh) * 2048 + s0) = pv;
      } else {
#pragma unroll
        for (int r = 0; r < 4; ++r) {
          int grow = grow0 + r;
          float v = acc[m][n][r] + bv;
          if (DOGELU) v = fast_gelu(v);
          if (RESMODE == 1) v += ((const float*)res)[(size_t)grow * N + gcol];
          if (RESMODE == 2) v += bf2f(((const u16*)res)[(size_t)grow * N + gcol]);
          if (OUTMODE == 1)
            ((u16*)Cout)[(size_t)grow * N + gcol] = f2bf(v);
          else
            ((float*)Cout)[(size_t)grow * N + gcol] = v;
        }
      }
    }
  }
}

// ---------------- W2 GEMM (BK=64): fp32 out = ff1 * w2t^T + b2 + bf16 residual ----------------
// 64x128 tile, BK=64, 4 waves 2x2 (wave = 32x64), 64 iterations for K=4096 (vs 128 at BK=32):
// barrier count halves, 16 MFMA/iter/wave. Same proven 2-phase skeleton + R6-verified
// 8-chunk XOR layout: LDS[row][p] holds logical chunk p ^ (row&7); staged via pre-swizzled
// global src, dest = burst*4096B + t*16B (wave-uniform + lane*16). Reads undo XOR, 2-way free.
__global__ __launch_bounds__(256, 3) void gemm_w2(const u16* __restrict__ A,
                                                  const u16* __restrict__ Bt,
                                                  const float* __restrict__ bias,
                                                  const u16* __restrict__ res,
                                                  float* __restrict__ Cout, int M, int N,
                                                  int K) {
  __shared__ u16 As[2][64 * 64];
  __shared__ u16 Bs[2][128 * 64];
  const int t = threadIdx.x;
  const int w = t >> 6, l = t & 63, g = l >> 4, c = l & 15;
  const int wr = w >> 1, wc = w & 1;
  const int nTn = N >> 7;  // 8
  const int bid = xcd_swz(blockIdx.x, gridDim.x);
  const int tm = bid / nTn, tn = bid % nTn;

  f32x4 acc[2][4];
#pragma unroll
  for (int m = 0; m < 2; ++m)
#pragma unroll
    for (int n = 0; n < 4; ++n) acc[m][n] = (f32x4){0.f, 0.f, 0.f, 0.f};

  const int srow = t >> 3, sph = t & 7;           // row 0..31 per burst, phys chunk
  const int sch = sph ^ (srow & 7);               // pre-swizzled global chunk
  const u16* Ag = A + (size_t)(tm * 64 + srow) * K + sch * 8;
  const u16* Bg = Bt + (size_t)(tn * 128 + srow) * K + sch * 8;

#define W2STG(buf, k0)                                                                 \
  {                                                                                    \
    _Pragma("unroll") for (int i = 0; i < 2; ++i)                                      \
        gl_lds16(Ag + (size_t)(i * 32) * K + (k0), (u16*)As[buf] + i * 2048 + t * 8);  \
    _Pragma("unroll") for (int i = 0; i < 4; ++i)                                      \
        gl_lds16(Bg + (size_t)(i * 32) * K + (k0), (u16*)Bs[buf] + i * 2048 + t * 8);  \
  }

  const int nt = K >> 6;  // 64
  W2STG(0, 0);
  __syncthreads();
  int cur = 0;

  for (int it = 0; it < nt; ++it) {
    if (it + 1 < nt) W2STG(cur ^ 1, (it + 1) * 64);
    bf16x8 af[2][2], bfr[4][2];
#pragma unroll
    for (int m = 0; m < 2; ++m) {
      int ar = wr * 32 + m * 16 + c;
#pragma unroll
      for (int kk = 0; kk < 2; ++kk)
        af[m][kk] = *(const bf16x8*)(As[cur] + ar * 64 + ((kk * 4 + g) ^ (c & 7)) * 8);
    }
#pragma unroll
    for (int n = 0; n < 4; ++n) {
      int br = wc * 64 + n * 16 + c;
#pragma unroll
      for (int kk = 0; kk < 2; ++kk)
        bfr[n][kk] = *(const bf16x8*)(Bs[cur] + br * 64 + ((kk * 4 + g) ^ (c & 7)) * 8);
    }
#pragma unroll
    for (int kk = 0; kk < 2; ++kk)
#pragma unroll
      for (int m = 0; m < 2; ++m)
#pragma unroll
        for (int n = 0; n < 4; ++n)
          acc[m][n] =
              __builtin_amdgcn_mfma_f32_16x16x32_bf16(af[m][kk], bfr[n][kk], acc[m][n], 0, 0, 0);
    __syncthreads();
    cur ^= 1;
  }
#undef W2STG

#pragma unroll
  for (int m = 0; m < 2; ++m) {
    int grow0 = tm * 64 + wr * 32 + m * 16 + g * 4;
#pragma unroll
    for (int n = 0; n < 4; ++n) {
      int gcol = tn * 128 + wc * 64 + n * 16 + c;
      float bv = bias[gcol];
#pragma unroll
      for (int r = 0; r < 4; ++r) {
        int grow = grow0 + r;
        float v = acc[m][n][r] + bv + bf2f(res[(size_t)grow * N + gcol]);
        Cout[(size_t)grow * N + gcol] = v;
      }
    }
  }
}

// ---------------- fused windowed+global attention (R15 verbatim) ----------------
__global__ __launch_bounds__(512, 3) void attn_fwd(const u16* __restrict__ qkv,
                                                   const u16* __restrict__ vt,
                                                   const u64* __restrict__ isgq,
                                                   u16* __restrict__ ctx) {
  __shared__ u16 Ks[2][64 * 64];   // [s][dh], chunk-XOR swizzled by (s&7)
  __shared__ u16 Vs[2][64 * 64];   // [dh][s], chunk-XOR swizzled by (dh&7)
  __shared__ u16 Ps[8][16 * 64];   // per-wave P, [q][s], swizzled by (q&7)
  const int t = threadIdx.x, w = t >> 6, l = t & 63, g = l >> 4, c = l & 15;
  const int bid = xcd_swz(blockIdx.x, 512);
  const int qb = bid & 15, h = (bid >> 4) & 15, b = bid >> 8;
  const int q0 = qb * 128 + w * 16;
  const float C2 = 0.18033688011112042f;  // 0.125 * log2(e)

  bf16x8 aq[2];
#pragma unroll
  for (int kf = 0; kf < 2; ++kf) {
    bf16x8 raw = *(const bf16x8*)(qkv + (size_t)(b * 2048 + q0 + c) * 3072 +
                                  h * 64 + kf * 32 + g * 8);
#pragma unroll
    for (int j = 0; j < 8; ++j) aq[kf][j] = (__bf16)((float)raw[j] * C2);
  }

  const u64 qw = isgq[b * 32 + (q0 >> 6)];
  bool qflag[4];
#pragma unroll
  for (int r = 0; r < 4; ++r) qflag[r] = (qw >> ((q0 & 63) + g * 4 + r)) & 1;

  bf16x8 vone;
#pragma unroll
  for (int j = 0; j < 8; ++j) vone[j] = (__bf16)1.0f;

  int poff[4][4];
#pragma unroll
  for (int n = 0; n < 4; ++n)
#pragma unroll
    for (int r = 0; r < 4; ++r) {
      int qr = g * 4 + r, scol = n * 16 + c;
      poff[n][r] = qr * 128 + ((scol * 2) ^ ((qr & 7) << 4));
    }

  f32x4 o[4], ol;
#pragma unroll
  for (int n = 0; n < 4; ++n) o[n] = (f32x4){0.f, 0.f, 0.f, 0.f};
  ol = (f32x4){0.f, 0.f, 0.f, 0.f};

  const int stR = t >> 3, stC = t & 7;
  const int qa0 = q0 + g * 4;

#define STAGE(buf, kt)                                                                       \
  {                                                                                          \
    int ch_ = stC ^ (stR & 7);                                                               \
    gl_lds16(qkv + (size_t)(b * 2048 + (kt)*64 + stR) * 3072 + 1024 + h * 64 + ch_ * 8,      \
             (u16*)Ks[buf] + stR * 64 + stC * 8);                                            \
    gl_lds16(vt + (size_t)((b * 16 + h) * 64 + stR) * 2048 + (kt)*64 + ch_ * 8,              \
             (u16*)Vs[buf] + stR * 64 + stC * 8);                                            \
  }

  STAGE(0, 0);
  __syncthreads();
  int cur = 0;

  for (int kt = 0; kt < 32; ++kt) {
    if (kt + 1 < 32) STAGE(cur ^ 1, kt + 1);
    const u64 kw = isgq[b * 32 + kt];

    f32x4 sf[4];
#pragma unroll
    for (int n = 0; n < 4; ++n) sf[n] = (f32x4){0.f, 0.f, 0.f, 0.f};
#pragma unroll
    for (int n = 0; n < 4; ++n) {
      int srw = n * 16 + c;
#pragma unroll
      for (int kf = 0; kf < 2; ++kf) {
        bf16x8 kb = *(const bf16x8*)((const char*)Ks[cur] + srw * 128 +
                                     ((kf * 64 + g * 16) ^ ((srw & 7) << 4)));
        sf[n] = __builtin_amdgcn_mfma_f32_16x16x32_bf16(aq[kf], kb, sf[n], 0, 0, 0);
      }
    }

    const int k64 = kt * 64;
    if (k64 >= q0 - 241 && k64 <= q0 + 193) {
#pragma unroll
      for (int n = 0; n < 4; ++n)
#pragma unroll
        for (int r = 0; r < 4; ++r)
          *(u16*)((char*)Ps[w] + poff[n][r]) = f2bf(fexp2(sf[n][r]));
    } else {
#pragma unroll
      for (int n = 0; n < 4; ++n) {
        int kcol = k64 + n * 16 + c;
        bool kfl = (kw >> (n * 16 + c)) & 1;
#pragma unroll
        for (int r = 0; r < 4; ++r) {
          int d = qa0 + r - kcol;
          bool ok = ((unsigned)(d + 256) <= 512u) || qflag[r] || kfl;
          float p = fexp2(ok ? sf[n][r] : -1e30f);
          *(u16*)((char*)Ps[w] + poff[n][r]) = f2bf(p);
        }
      }
    }

#pragma unroll
    for (int kf = 0; kf < 2; ++kf) {
      bf16x8 pa = *(const bf16x8*)((const char*)Ps[w] + c * 128 +
                                   ((kf * 64 + g * 16) ^ ((c & 7) << 4)));
#pragma unroll
      for (int n = 0; n < 4; ++n) {
        int dh = n * 16 + c;
        bf16x8 vb = *(const bf16x8*)((const char*)Vs[cur] + dh * 128 +
                                     ((kf * 64 + g * 16) ^ ((dh & 7) << 4)));
        o[n] = __builtin_amdgcn_mfma_f32_16x16x32_bf16(pa, vb, o[n], 0, 0, 0);
      }
      ol = __builtin_amdgcn_mfma_f32_16x16x32_bf16(pa, vone, ol, 0, 0, 0);
    }
    __syncthreads();
    cur ^= 1;
  }
#undef STAGE

#pragma unroll
  for (int r = 0; r < 4; ++r) {
    float inv = 1.0f / ol[r];
    int qg = q0 + g * 4 + r;
#pragma unroll
    for (int n = 0; n < 4; ++n)
      ctx[(size_t)(b * 2048 + qg) * 1024 + h * 64 + n * 16 + c] = f2bf(o[n][r] * inv);
  }
}

// ---------------- launcher ----------------

extern "C" void kernel_launch(void* const* d_in, const int* in_sizes, int n_in,
                              void* d_out, int out_size, void* d_ws, size_t ws_size,
                              hipStream_t stream) {
  (void)in_sizes; (void)n_in; (void)out_size; (void)ws_size;
  const float* x = (const float*)d_in[0];
  const unsigned char* isg = (const unsigned char*)d_in[1];
  const float* Wq = (const float*)d_in[2];
  const float* bq = (const float*)d_in[3];
  const float* Wk = (const float*)d_in[4];
  const float* bk = (const float*)d_in[5];
  const float* Wv = (const float*)d_in[6];
  const float* bv = (const float*)d_in[7];
  const float* Wo = (const float*)d_in[8];
  const float* bo = (const float*)d_in[9];
  const float* ln1g = (const float*)d_in[10];
  const float* ln1b = (const float*)d_in[11];
  const float* ln2g = (const float*)d_in[12];
  const float* ln2b = (const float*)d_in[13];
  const float* W1 = (const float*)d_in[14];
  const float* b1 = (const float*)d_in[15];
  const float* W2 = (const float*)d_in[16];
  const float* b2 = (const float*)d_in[17];

  char* ws = (char*)d_ws;
  u16* wqkvt = (u16*)(ws);                    // [3072][1024] bf16, 6MB (wot follows contiguously)
  u16* wot   = (u16*)(ws + 6 * MBYTE);        // [1024][1024], 2MB
  u16* w1t   = (u16*)(ws + 8 * MBYTE);        // [4096][1024], 8MB
  u16* w2t   = (u16*)(ws + 16 * MBYTE);       // [1024][4096], 8MB
  float* bqkv = (float*)(ws + 24 * MBYTE);    // [3072]
  u64* isgq  = (u64*)(ws + 24 * MBYTE + 65536);  // 64 qwords
  u16* hbuf  = (u16*)(ws + 25 * MBYTE);       // [4096][1024] bf16 (h, then h2)
  u16* qkvb  = (u16*)(ws + 33 * MBYTE);       // [4096][3072] bf16, 24MB (V slice unused)
  u16* vtb   = (u16*)(ws + 57 * MBYTE);       // [B*H*64][2048] bf16, 8MB
  u16* ctx   = (u16*)(ws + 65 * MBYTE);       // [4096][1024] bf16, 8MB
  u16* x1b   = (u16*)(ws + 73 * MBYTE);       // [4096][1024] bf16 residual stream, 8MB
  u16* ff1   = (u16*)(ws + 33 * MBYTE);       // [4096][4096] bf16, 32MB (aliases qkv+vt, dead by then)

  transpose_all<<<12301, 256, 0, stream>>>(Wq, Wk, Wv, Wo, W1, W2, wqkvt, w1t, w2t,
                                           isg, isgq, bq, bk, bv, bqkv);

  layernorm_k<false><<<4096, 256, 0, stream>>>(x, ln1g, ln1b, hbuf);
  gemm_bt<4, 1, false, 0, true><<<768, 256, 0, stream>>>(hbuf, wqkvt, bqkv, nullptr,
                                                         qkvb, vtb, 4096, 3072, 1024);
  attn_fwd<<<512, 512, 0, stream>>>(qkvb, vtb, isgq, ctx);
  gemm_bt<2, 1, false, 1, false><<<512, 256, 0, stream>>>(ctx, wot, bo, x, x1b, nullptr,
                                                          4096, 1024, 1024);
  layernorm_k<true><<<4096, 256, 0, stream>>>(x1b, ln2g, ln2b, hbuf);
  gemm_bt<4, 1, true, 0, false><<<1024, 256, 0, stream>>>(hbuf, w1t, b1, nullptr, ff1,
                                                          nullptr, 4096, 4096, 1024);
  gemm_w2<<<512, 256, 0, stream>>>(ff1, w2t, b2, x1b, (float*)d_out, 4096, 1024, 4096);
}